// Round 9
// baseline (228.214 us; speedup 1.0000x reference)
//
#include <hip/hip_runtime.h>

#define NTOK 32768

typedef __attribute__((ext_vector_type(8))) short short8;
typedef __attribute__((ext_vector_type(4))) short short4_t;
typedef __attribute__((ext_vector_type(4))) float f32x4;

__device__ __forceinline__ short f2b(float f) {
    union { float f; unsigned u; } v; v.f = f;
    unsigned r = v.u + 0x7fffu + ((v.u >> 16) & 1u);
    return (short)(r >> 16);
}
__device__ __forceinline__ float b2f(short s) {
    union { float f; unsigned u; } v;
    v.u = ((unsigned)(unsigned short)s) << 16;
    return v.f;
}

// ------- setup: repack conv weights, bf16 conversions, init accumulators -------
__global__ void k_repack(const float* __restrict__ w1, const float* __restrict__ w2,
                         const float* __restrict__ w8, const float* __restrict__ wef,
                         const float* __restrict__ wq, const float* __restrict__ bEF,
                         short* __restrict__ wb1, short* __restrict__ wb2,
                         short* __restrict__ wb8, short* __restrict__ wefb,
                         short* __restrict__ wqb, float* __restrict__ kp,
                         float* __restrict__ vp, float* __restrict__ qd)
{
    int i = blockIdx.x * 256 + threadIdx.x;
    if (i >= 2349312) return;
    if (i >= 2347008) { qd[i - 2347008] = 0.f; return; }
    if (i >= 2338816) {
        int j = i - 2338816;
        float v = bEF[j & 63];
        kp[j] = v; vp[j] = v; return;
    }
    if (i >= 2322432) { int j = i - 2322432; wqb[j] = f2b(wq[j]); return; }
    if (i >= 225280)  { int j = i - 225280;  wefb[j] = f2b(wef[j]); return; }
    if (i >= 221184)  { int j = i - 221184;  wb8[j] = f2b(w8[j]); return; }
    int sel = i >= 110592;
    int j = sel ? i - 110592 : i;
    int tap = j >> 12;
    int r = j & 4095;
    int oc = r >> 6, ic = r & 63;
    const float* w = sel ? w2 : w1;
    short* o = sel ? wb2 : wb1;
    o[j] = f2b(w[(oc * 64 + ic) * 27 + tap]);
}

// ---------------- fused LayerNorm + QKVV GEMM (MFMA), bf16 W ----------------
// qkvvb layout: bf16 [isel(4)][b(2)][h(4)][d(16)][N]  (512 rows x 32768 = 32 MB)
__global__ __launch_bounds__(256) void k_ln_qkvv(
    const float* __restrict__ x, const float* __restrict__ lnw,
    const float* __restrict__ lnb, const short* __restrict__ wqb,
    short* __restrict__ qkvvb)
{
    __shared__ __align__(16) short Wl[256 * 72];
    __shared__ __align__(16) short tr[256 * 72];
    __shared__ float red1[4][64], red2[4][64];
    __shared__ float mu_s[64], rs_s[64];
    short* al = tr;                                 // bf16 [64 t][72]

    int bid = blockIdx.x;
    int b = bid >> 9;
    int n0 = (bid & 511) << 6;
    int tid = threadIdx.x;

    for (int i = tid; i < 2048; i += 256) {
        int out = i >> 3, q8 = (i & 7) * 8;
        *(short8*)&Wl[out * 72 + q8] = *(const short8*)&wqb[out * 64 + q8];
    }

    int t = tid & 63, cq = tid >> 6;
    float xr[16];
    float s1 = 0.f, s2 = 0.f;
    const float* xb = x + (((size_t)(b * 64 + cq * 16)) << 15) + n0 + t;
#pragma unroll
    for (int j = 0; j < 16; ++j) {
        float v = xb[(size_t)j << 15];
        xr[j] = v; s1 += v; s2 += v * v;
    }
    red1[cq][t] = s1; red2[cq][t] = s2;
    __syncthreads();
    if (tid < 64) {
        float a = red1[0][tid] + red1[1][tid] + red1[2][tid] + red1[3][tid];
        float q = red2[0][tid] + red2[1][tid] + red2[2][tid] + red2[3][tid];
        float mu = a * (1.f / 64.f);
        float var = q * (1.f / 64.f) - mu * mu;
        mu_s[tid] = mu;
        rs_s[tid] = rsqrtf(var + 1e-5f);
    }
    __syncthreads();
    {
        float mu = mu_s[t], rs = rs_s[t];
        short8 p0, p1;
#pragma unroll
        for (int j = 0; j < 8; ++j) {
            int c = cq * 16 + j;
            p0[j] = f2b((xr[j] - mu) * rs * lnw[c] + lnb[c]);
        }
#pragma unroll
        for (int j = 0; j < 8; ++j) {
            int c = cq * 16 + 8 + j;
            p1[j] = f2b((xr[8 + j] - mu) * rs * lnw[c] + lnb[c]);
        }
        *(short8*)&al[t * 72 + cq * 16] = p0;
        *(short8*)&al[t * 72 + cq * 16 + 8] = p1;
    }
    __syncthreads();

    int w = tid >> 6, lane = tid & 63, l15 = lane & 15, quad = lane >> 4;
    f32x4 acc[4][4];
#pragma unroll
    for (int mt = 0; mt < 4; ++mt)
#pragma unroll
        for (int nt = 0; nt < 4; ++nt) acc[mt][nt] = (f32x4){0.f, 0.f, 0.f, 0.f};
#pragma unroll
    for (int ks = 0; ks < 2; ++ks) {
        short8 af[4], bf[4];
#pragma unroll
        for (int mt = 0; mt < 4; ++mt)
            af[mt] = *(const short8*)&al[(mt * 16 + l15) * 72 + quad * 8 + ks * 32];
#pragma unroll
        for (int nt = 0; nt < 4; ++nt)
            bf[nt] = *(const short8*)&Wl[(w * 64 + nt * 16 + l15) * 72 + quad * 8 + ks * 32];
#pragma unroll
        for (int mt = 0; mt < 4; ++mt)
#pragma unroll
            for (int nt = 0; nt < 4; ++nt)
                acc[mt][nt] = __builtin_amdgcn_mfma_f32_16x16x32_bf16(af[mt], bf[nt], acc[mt][nt], 0, 0, 0);
    }
    __syncthreads();

#pragma unroll
    for (int mt = 0; mt < 4; ++mt)
#pragma unroll
        for (int nt = 0; nt < 4; ++nt) {
            int out = w * 64 + nt * 16 + l15;
            short4_t sv;
#pragma unroll
            for (int r = 0; r < 4; ++r) sv[r] = f2b(acc[mt][nt][r]);
            *(short4_t*)&tr[out * 72 + mt * 16 + quad * 4] = sv;
        }
    __syncthreads();
    for (int i = tid; i < 2048; i += 256) {
        int o = i >> 3, tq = (i & 7) * 8;
        short8 v = *(const short8*)&tr[o * 72 + tq];
        int isel = o >> 6, h = (o >> 4) & 3, d = o & 15;
        *(short8*)&qkvvb[((size_t)(((isel * 2 + b) * 4 + h) * 16 + d) << 15) + n0 + tq] = v;
    }
}

// ------- merged MFMA: k/v projections + q.k logits + L2-norm accumulators -------
// Round-9: global reads were 16-row-SCATTERED (rows 64KB apart selected by l15 ->
// 16 transactions per load instr) with 1 wave/SIMD = no latency hiding. Now:
// cooperative coalesced LDS staging (4 chunks of 256 cols; 512B-contiguous row
// reads, 14 independent 16B loads/thread) -> MFMA frags via ds_read_b128.
// Row pitch 280 shorts (140 dw = 12 mod 32) spreads 16 frag rows uniformly over
// bank groups (conflict-free, no swizzle). Reduction/atomics tail unchanged.
__global__ __launch_bounds__(256) void k_pq(
    const short* __restrict__ qkvvb, const short* __restrict__ wefb,
    float* __restrict__ kp, float* __restrict__ vp, float* __restrict__ qd,
    float* __restrict__ qn_acc, float* __restrict__ kn_acc)
{
    __shared__ __align__(16) short q_l[16 * 280];
    __shared__ __align__(16) short k_l[16 * 280];
    __shared__ __align__(16) short v_l[16 * 280];
    __shared__ __align__(16) short w_l[64 * 280];
    __shared__ float redb[3][64][38];
    int kc = blockIdx.x, bh = blockIdx.y;
    int tid = threadIdx.x;
    int w = tid >> 6, lane = tid & 63, l15 = lane & 15, quad = lane >> 4;

    f32x4 acck[4], accv[4], accqd, accqq, acckk;
#pragma unroll
    for (int nt = 0; nt < 4; ++nt) {
        acck[nt] = (f32x4){0.f, 0.f, 0.f, 0.f};
        accv[nt] = (f32x4){0.f, 0.f, 0.f, 0.f};
    }
    accqd = (f32x4){0.f, 0.f, 0.f, 0.f};
    accqq = (f32x4){0.f, 0.f, 0.f, 0.f};
    acckk = (f32x4){0.f, 0.f, 0.f, 0.f};

    int lc_base = w * 64 + quad * 8;   // chunk-local col for this wave (+ks*32)

    for (int chunk = 0; chunk < 4; ++chunk) {
        int n0 = kc * 1024 + chunk * 256;
        __syncthreads();   // prev chunk's frag reads done
        // stage q(512) k(512) v(512) wef(2048) 16B-items, coalesced per row
        for (int i = tid; i < 3584; i += 256) {
            const short* src;
            short* dst;
            if (i < 1536) {
                int t = i >> 9;              // 0=q 1=k 2=v
                int j = i & 511;
                int row = j >> 5, c16 = j & 31;
                int grow = (t == 0 ? 0 : (t == 1 ? 128 : 384)) + bh * 16 + row;
                src = &qkvvb[((size_t)grow << 15) + n0 + c16 * 8];
                dst = (t == 0 ? q_l : (t == 1 ? k_l : v_l)) + row * 280 + c16 * 8;
            } else {
                int j = i - 1536;            // wef: 64 rows x 32 chunks
                int row = j >> 5, c16 = j & 31;
                src = &wefb[((size_t)row << 15) + n0 + c16 * 8];
                dst = w_l + row * 280 + c16 * 8;
            }
            *(short8*)dst = *(const short8*)src;
        }
        __syncthreads();   // staged chunk visible
#pragma unroll
        for (int ks = 0; ks < 2; ++ks) {
            int lc = lc_base + ks * 32;
            short8 qf = *(const short8*)&q_l[l15 * 280 + lc];
            short8 kf = *(const short8*)&k_l[l15 * 280 + lc];
            short8 vf = *(const short8*)&v_l[l15 * 280 + lc];
            accqd = __builtin_amdgcn_mfma_f32_16x16x32_bf16(qf, kf, accqd, 0, 0, 0);
            accqq = __builtin_amdgcn_mfma_f32_16x16x32_bf16(qf, qf, accqq, 0, 0, 0);
            acckk = __builtin_amdgcn_mfma_f32_16x16x32_bf16(kf, kf, acckk, 0, 0, 0);
#pragma unroll
            for (int nt = 0; nt < 4; ++nt) {
                short8 wf = *(const short8*)&w_l[(nt * 16 + l15) * 280 + lc];
                acck[nt] = __builtin_amdgcn_mfma_f32_16x16x32_bf16(kf, wf, acck[nt], 0, 0, 0);
                accv[nt] = __builtin_amdgcn_mfma_f32_16x16x32_bf16(vf, wf, accv[nt], 0, 0, 0);
            }
        }
    }

    int diag = (quad == (l15 >> 2));
    float qqv = diag ? accqq[l15 & 3] : 0.f;
    float kkv = diag ? acckk[l15 & 3] : 0.f;
    __syncthreads();   // frag reads done before redb aliases nothing (separate buf; ordering only)
    if (w > 0) {
        float* p = &redb[w - 1][lane][0];
#pragma unroll
        for (int nt = 0; nt < 4; ++nt)
#pragma unroll
            for (int r = 0; r < 4; ++r) { p[nt * 4 + r] = acck[nt][r]; p[16 + nt * 4 + r] = accv[nt][r]; }
#pragma unroll
        for (int r = 0; r < 4; ++r) p[32 + r] = accqd[r];
        p[36] = qqv; p[37] = kkv;
    }
    __syncthreads();
    if (w == 0) {
#pragma unroll
        for (int wv = 0; wv < 3; ++wv) {
            const float* p = &redb[wv][lane][0];
#pragma unroll
            for (int nt = 0; nt < 4; ++nt)
#pragma unroll
                for (int r = 0; r < 4; ++r) { acck[nt][r] += p[nt * 4 + r]; accv[nt][r] += p[16 + nt * 4 + r]; }
#pragma unroll
            for (int r = 0; r < 4; ++r) accqd[r] += p[32 + r];
            qqv += p[36]; kkv += p[37];
        }
        int d = quad * 4;
#pragma unroll
        for (int nt = 0; nt < 4; ++nt)
#pragma unroll
            for (int r = 0; r < 4; ++r) {
                int idx = (bh * 16 + d + r) * 64 + nt * 16 + l15;
                atomicAdd(&kp[idx], acck[nt][r]);
                atomicAdd(&vp[idx], accv[nt][r]);
            }
#pragma unroll
        for (int r = 0; r < 4; ++r)
            atomicAdd(&qd[bh * 256 + (d + r) * 16 + l15], accqd[r]);
        if (diag) {
            atomicAdd(&qn_acc[bh * 16 + l15], qqv);
            atomicAdd(&kn_acc[bh * 16 + l15], kkv);
        }
    }
}

// ---------------- fused x_ca + spatial attention — MFMA version (round-5 proven) ----------------
__global__ __launch_bounds__(256) void k_attn(
    const short* __restrict__ qkvvb, const float* __restrict__ qd,
    const float* __restrict__ qn_acc, const float* __restrict__ kn_acc,
    const float* __restrict__ temp1, const float* __restrict__ kp,
    const float* __restrict__ vp, const float* __restrict__ temp2,
    short* __restrict__ xsab, short* __restrict__ xcab)
{
    __shared__ float kl[16][68];
    __shared__ float vl[16][68];
    __shared__ float alca[16][17];
    __shared__ float iqs[16], iks[16];
    __shared__ __align__(16) short Pl[4][64][72];   // per-wave P, XOR-swizzled cols
    __shared__ short Ol[4][64][17];                 // per-wave O transpose staging
    int bh = blockIdx.y; int b = bh >> 2, h = bh & 3;
    int tid = threadIdx.x;
    for (int i = tid; i < 1024; i += 256) {
        kl[i >> 6][i & 63] = kp[bh * 1024 + i];
        vl[i >> 6][i & 63] = vp[bh * 1024 + i];
    }
    if (tid < 32) {
        int j = tid & 15;
        float v = (tid < 16) ? qn_acc[bh * 16 + j] : kn_acc[bh * 16 + j];
        float rv = 1.f / fmaxf(sqrtf(v), 1e-12f);
        if (tid < 16) iqs[j] = rv; else iks[j] = rv;
    }
    __syncthreads();
    {   // CA softmax: row r = tid>>4 (lanes r*16..r*16+15 contiguous in-wave)
        int r = tid >> 4, e = tid & 15;
        float v = qd[bh * 256 + tid] * iqs[r] * iks[e] * temp1[h];
        float mx = v;
#pragma unroll
        for (int m = 1; m < 16; m <<= 1) mx = fmaxf(mx, __shfl_xor(mx, m));
        float ex = __expf(v - mx);
        float s = ex;
#pragma unroll
        for (int m = 1; m < 16; m <<= 1) s += __shfl_xor(s, m);
        alca[r][e] = ex / s;
    }
    __syncthreads();

    int w = tid >> 6, lane = tid & 63, l15 = lane & 15, quad = lane >> 4;
    int tw = (blockIdx.x << 8) + w * 64;
    float t2 = temp2[h];
    const short8 zero8 = {0, 0, 0, 0, 0, 0, 0, 0};
    int xs = (l15 & 7) << 3;                        // Pl bank swizzle (per token row)

    // ---- B-frags: Qn[tok][d] (k = d, zero-padded 16..31) ----
    short8 qb[4];
    if (quad < 2) {
#pragma unroll
        for (int tnt = 0; tnt < 4; ++tnt) {
            short8 v;
#pragma unroll
            for (int j = 0; j < 8; ++j) {
                int d = quad * 8 + j;
                short qv = qkvvb[(((size_t)(bh * 16 + d)) << 15) + tw + tnt * 16 + l15];
                v[j] = f2b(b2f(qv) * iqs[d]);
            }
            qb[tnt] = v;
        }
    } else {
#pragma unroll
        for (int tnt = 0; tnt < 4; ++tnt) qb[tnt] = zero8;
    }
    // ---- A-frags: Kp[p][d] from kl ----
    short8 ka[4];
    if (quad < 2) {
#pragma unroll
        for (int pmt = 0; pmt < 4; ++pmt) {
            short8 v;
#pragma unroll
            for (int j = 0; j < 8; ++j) v[j] = f2b(kl[quad * 8 + j][pmt * 16 + l15]);
            ka[pmt] = v;
        }
    } else {
#pragma unroll
        for (int pmt = 0; pmt < 4; ++pmt) ka[pmt] = zero8;
    }

    // ---- S^T = Kp . Qn^T : 16 MFMAs ----
    f32x4 st[4][4];
#pragma unroll
    for (int pmt = 0; pmt < 4; ++pmt)
#pragma unroll
        for (int tnt = 0; tnt < 4; ++tnt) st[pmt][tnt] = (f32x4){0.f, 0.f, 0.f, 0.f};
#pragma unroll
    for (int pmt = 0; pmt < 4; ++pmt)
#pragma unroll
        for (int tnt = 0; tnt < 4; ++tnt)
            st[pmt][tnt] = __builtin_amdgcn_mfma_f32_16x16x32_bf16(ka[pmt], qb[tnt], st[pmt][tnt], 0, 0, 0);

    // ---- softmax over p (lane holds 16 of 64 p for its token col) ----
#pragma unroll
    for (int tnt = 0; tnt < 4; ++tnt) {
        int tok = tnt * 16 + l15;
        float v[16];
        float mx = -1e30f;
#pragma unroll
        for (int pmt = 0; pmt < 4; ++pmt)
#pragma unroll
            for (int r = 0; r < 4; ++r) {
                float x = st[pmt][tnt][r] * t2;
                v[pmt * 4 + r] = x; mx = fmaxf(mx, x);
            }
        mx = fmaxf(mx, __shfl_xor(mx, 16));
        mx = fmaxf(mx, __shfl_xor(mx, 32));
        float s = 0.f;
#pragma unroll
        for (int i2 = 0; i2 < 16; ++i2) { v[i2] = __expf(v[i2] - mx); s += v[i2]; }
        s += __shfl_xor(s, 16);
        s += __shfl_xor(s, 32);
        float inv = 1.f / s;
#pragma unroll
        for (int pmt = 0; pmt < 4; ++pmt)
#pragma unroll
            for (int t = 0; t < 2; ++t) {
                unsigned lo = (unsigned short)f2b(v[pmt * 4 + 2 * t] * inv);
                unsigned hi = (unsigned short)f2b(v[pmt * 4 + 2 * t + 1] * inv);
                int col = (pmt * 16 + quad * 4 + 2 * t) ^ xs;
                *(unsigned*)&Pl[w][tok][col] = lo | (hi << 16);
            }
    }

    // ---- O = P . Vp : B-frags from vl (k = p, full 64) ----
    short8 vb[2];
#pragma unroll
    for (int ks = 0; ks < 2; ++ks) {
        short8 t;
#pragma unroll
        for (int j = 0; j < 8; ++j) t[j] = f2b(vl[l15][quad * 8 + ks * 32 + j]);
        vb[ks] = t;
    }
    f32x4 vo[4];
#pragma unroll
    for (int mt = 0; mt < 4; ++mt) vo[mt] = (f32x4){0.f, 0.f, 0.f, 0.f};
#pragma unroll
    for (int mt = 0; mt < 4; ++mt) {
        int tok = mt * 16 + l15;
#pragma unroll
        for (int ks = 0; ks < 2; ++ks) {
            short8 pa = *(const short8*)&Pl[w][tok][(quad * 8 + ks * 32) ^ xs];
            vo[mt] = __builtin_amdgcn_mfma_f32_16x16x32_bf16(pa, vb[ks], vo[mt], 0, 0, 0);
        }
    }

    // ---- CA: x_ca = Vca . alca^T (k = e, zero-padded 16..31) ----
    short8 ab[4], bb;
    if (quad < 2) {
        short8 t;
#pragma unroll
        for (int j = 0; j < 8; ++j) t[j] = f2b(alca[l15][quad * 8 + j]);
        bb = t;
#pragma unroll
        for (int mt = 0; mt < 4; ++mt) {
            short8 u;
#pragma unroll
            for (int j = 0; j < 8; ++j)
                u[j] = qkvvb[(((size_t)(256 + bh * 16 + quad * 8 + j)) << 15) + tw + mt * 16 + l15];
            ab[mt] = u;
        }
    } else {
        bb = zero8;
#pragma unroll
        for (int mt = 0; mt < 4; ++mt) ab[mt] = zero8;
    }
    f32x4 ca[4];
#pragma unroll
    for (int mt = 0; mt < 4; ++mt) ca[mt] = (f32x4){0.f, 0.f, 0.f, 0.f};
#pragma unroll
    for (int mt = 0; mt < 4; ++mt)
        ca[mt] = __builtin_amdgcn_mfma_f32_16x16x32_bf16(ab[mt], bb, ca[mt], 0, 0, 0);

    // ---- CA direct stores (lane: tok=mt*16+quad*4+r, d=l15; 32B-coalesced) ----
#pragma unroll
    for (int mt = 0; mt < 4; ++mt)
#pragma unroll
        for (int r = 0; r < 4; ++r) {
            int tok = tw + mt * 16 + quad * 4 + r;
            xcab[((size_t)(b * NTOK + tok)) * 64 + h * 16 + l15] = f2b(ca[mt][r]);
        }

    // ---- O via LDS transpose -> token-coalesced xsab writes ----
#pragma unroll
    for (int mt = 0; mt < 4; ++mt)
#pragma unroll
        for (int r = 0; r < 4; ++r)
            Ol[w][mt * 16 + quad * 4 + r][l15] = f2b(vo[mt][r]);
#pragma unroll
    for (int d = 0; d < 16; ++d) {
        short vv = Ol[w][lane][d];
        xsab[(size_t)b * 2097152 + (((size_t)(d * 4 + h)) << 15) + tw + lane] = vv;
    }
}

// ---------------- EPA epilogue (MFMA): proj + gamma + residual ----------------
__global__ __launch_bounds__(256) void k_epilogue(
    const float* __restrict__ x, const short* __restrict__ xsab,
    const short* __restrict__ xcab, const float* __restrict__ Wo1,
    const float* __restrict__ bo1, const float* __restrict__ Wo2,
    const float* __restrict__ bo2, const float* __restrict__ gamma,
    float* __restrict__ attn_skip, short* __restrict__ gA)
{
    __shared__ __align__(16) short Wl[64 * 72];    // rows 0-31: Wo1, 32-63: Wo2 (bf16)
    __shared__ __align__(16) short trS[256 * 72];  // bf16 [256 tok][72] for gA transpose
    int tid = threadIdx.x;
    int bidx = blockIdx.x;
    int b = bidx >> 7;
    int n0 = (bidx & 127) << 8;                    // 256 tokens per block
    for (int i = tid; i < 4096; i += 256) {
        int row = i >> 6, c = i & 63;
        float wv = (row < 32) ? Wo1[row * 64 + c] : Wo2[(row - 32) * 64 + c];
        Wl[row * 72 + c] = f2b(wv);
    }
    __syncthreads();

    int w = tid >> 6, lane = tid & 63, l15 = lane & 15, quad = lane >> 4;
    int tw = n0 + w * 64;
    const short* sa_base = xsab + (size_t)b * 2097152;
    const short* ca_base = xcab + (size_t)b * 2097152;

    f32x4 acc_sa[4][2], acc_ca[4][2];
#pragma unroll
    for (int mt = 0; mt < 4; ++mt)
#pragma unroll
        for (int nt = 0; nt < 2; ++nt) {
            acc_sa[mt][nt] = (f32x4){0.f, 0.f, 0.f, 0.f};
            acc_ca[mt][nt] = (f32x4){0.f, 0.f, 0.f, 0.f};
        }
#pragma unroll
    for (int ks = 0; ks < 2; ++ks) {
        int ko = quad * 8 + ks * 32;
        short8 b1[2], b2[2];
#pragma unroll
        for (int nt = 0; nt < 2; ++nt) {
            b1[nt] = *(const short8*)&Wl[(nt * 16 + l15) * 72 + ko];
            b2[nt] = *(const short8*)&Wl[(32 + nt * 16 + l15) * 72 + ko];
        }
#pragma unroll
        for (int mt = 0; mt < 4; ++mt) {
            int trow = tw + mt * 16 + l15;
            short8 a1 = *(const short8*)&sa_base[(size_t)trow * 64 + ko];
            short8 a2 = *(const short8*)&ca_base[(size_t)trow * 64 + ko];
#pragma unroll
            for (int nt = 0; nt < 2; ++nt) {
                acc_sa[mt][nt] = __builtin_amdgcn_mfma_f32_16x16x32_bf16(a1, b1[nt], acc_sa[mt][nt], 0, 0, 0);
                acc_ca[mt][nt] = __builtin_amdgcn_mfma_f32_16x16x32_bf16(a2, b2[nt], acc_ca[mt][nt], 0, 0, 0);
            }
        }
    }

    // fused residual: v = x + gamma*(acc + bias); write attn_skip (f32x4/lane);
    // stash bf16 into trS row=token (one scalar store per token — C rows differ!)
#pragma unroll
    for (int half = 0; half < 2; ++half) {   // 0: sa -> c in [0,32), 1: ca -> c in [32,64)
#pragma unroll
        for (int nt = 0; nt < 2; ++nt) {
            int c = half * 32 + nt * 16 + l15;
            float g = gamma[c];
            float bias = half ? bo2[c - 32] : bo1[c];
#pragma unroll
            for (int mt = 0; mt < 4; ++mt) {
                f32x4 a = half ? acc_ca[mt][nt] : acc_sa[mt][nt];
                int tbase = tw + mt * 16 + quad * 4;
                size_t gidx = (((size_t)(b * 64 + c)) << 15) + tbase;
                f32x4 xv = *(const f32x4*)&x[gidx];
                f32x4 o;
#pragma unroll
                for (int r = 0; r < 4; ++r) {
                    float v = xv[r] + g * (a[r] + bias);
                    o[r] = v;
                    trS[(w * 64 + mt * 16 + quad * 4 + r) * 72 + c] = f2b(v);
                }
                *(f32x4*)&attn_skip[gidx] = o;
            }
        }
    }
    __syncthreads();
    // coalesced NHWC gA write
    for (int i = tid; i < 2048; i += 256) {
        int tok = i >> 3, cq = (i & 7) * 8;
        short8 v = *(const short8*)&trS[tok * 72 + cq];
        *(short8*)&gA[((size_t)(b * NTOK + n0 + tok)) * 64 + cq] = v;
    }
}

// ---------------- MFMA implicit-GEMM 3x3x3 conv (round-8 proven) ----------------
template <int MODE>
__global__ __launch_bounds__(256) void k_conv3m(
    const short* __restrict__ gin, const short* __restrict__ wb,
    const float* __restrict__ bnw, const float* __restrict__ bnb,
    const float* __restrict__ skip, short* __restrict__ goutS,
    const short* __restrict__ wb8, const float* __restrict__ b8,
    float* __restrict__ io)
{
    __shared__ __align__(16) short inl_s[24480];   // [3z][6y][34x][40 icpad]
    __shared__ __align__(16) short wl_s[15360];    // 2 x [3][64][40]; MODE1 epi: a2(9216)+w8[64][80]@9216
    int bx = blockIdx.x;
    int bb = bx >> 8;
    int z0 = (bx >> 3) & 31;
    int y0 = (bx & 7) * 4;
    int tid = threadIdx.x;
    int lane = tid & 63, wv = tid >> 6;
    int l15 = lane & 15, quad = lane >> 4;
    int wo = tid >> 2, wq = tid & 3;

    f32x4 acc[2][4];
#pragma unroll
    for (int s = 0; s < 2; ++s)
#pragma unroll
        for (int nt = 0; nt < 4; ++nt) acc[s][nt] = (f32x4){0.f, 0.f, 0.f, 0.f};

    for (int chunk = 0; chunk < 2; ++chunk) {
        const short* wck = wb + chunk * 32 + wq * 8;
        // prefetch stages 0 AND 1 into regs (2-deep rotation)
        short8 wr[2][3];
#pragma unroll
        for (int t = 0; t < 3; ++t) {
            wr[0][t] = *(const short8*)&wck[(size_t)(t * 64 + wo) * 64];
            wr[1][t] = *(const short8*)&wck[(size_t)((3 + t) * 64 + wo) * 64];
        }
        __syncthreads();   // prev chunk's inl_s reads + wl_s buf reads done
        for (int i = tid; i < 2448; i += 256) {
            int p = i >> 2, icq = i & 3;
            int xi = p % 34; int t2 = p / 34; int yi = t2 % 6; int zi = t2 / 6;
            int gz = z0 + zi - 1, gy = y0 + yi - 1, gx = xi - 1;
            short8 v = {0, 0, 0, 0, 0, 0, 0, 0};
            if ((unsigned)gz < 32u && (unsigned)gy < 32u && (unsigned)gx < 32u)
                v = *(const short8*)&gin[((size_t)(bb * NTOK + gz * 1024 + gy * 32 + gx)) * 64 + chunk * 32 + icq * 8];
            *(short8*)&inl_s[p * 40 + icq * 8] = v;
        }
        // write stage-0 weights to buf0
#pragma unroll
        for (int t = 0; t < 3; ++t)
            *(short8*)&wl_s[(t * 64 + wo) * 40 + wq * 8] = wr[0][t];

#pragma unroll
        for (int kz = 0; kz < 3; ++kz)
#pragma unroll
        for (int ky = 0; ky < 3; ++ky) {
            const int sidx = kz * 3 + ky;
            __syncthreads();   // buf[sidx&1] writes visible; buf[(sidx+1)&1] reads (stage sidx-1) done
            if (sidx < 7) {
                // load stage sidx+2 into the slot just freed (held stage sidx)
#pragma unroll
                for (int t = 0; t < 3; ++t)
                    wr[sidx & 1][t] = *(const short8*)&wck[(size_t)(((sidx + 2) * 3 + t) * 64 + wo) * 64];
            }
            const short* wcur = &wl_s[(sidx & 1) * 7680];
            int rowb = (kz * 6 + wv + ky) * 34;
#pragma unroll
            for (int kx = 0; kx < 3; ++kx) {
                short8 bf[4];
#pragma unroll
                for (int nt = 0; nt < 4; ++nt)
                    bf[nt] = *(const short8*)&wcur[(kx * 64 + nt * 16 + l15) * 40 + quad * 8];
#pragma unroll
                for (int s = 0; s < 2; ++s) {
                    short8 af = *(const short8*)&inl_s[(rowb + s * 16 + l15 + kx) * 40 + quad * 8];
#pragma unroll
                    for (int nt = 0; nt < 4; ++nt)
                        acc[s][nt] = __builtin_amdgcn_mfma_f32_16x16x32_bf16(af, bf[nt], acc[s][nt], 0, 0, 0);
                }
            }
            if (sidx < 8) {
                // write stage sidx+1 (loaded at stage sidx-1 -> fully landed)
                short* wnext = &wl_s[((sidx + 1) & 1) * 7680];
#pragma unroll
                for (int t = 0; t < 3; ++t)
                    *(short8*)&wnext[(t * 64 + wo) * 40 + wq * 8] = wr[(sidx + 1) & 1][t];
            }
        }
    }
    __syncthreads();
    float rb = rsqrtf(1.f + 1e-5f);
    if (MODE == 0) {
        short* outS = inl_s;  // [128 pos][72 pad] bf16
#pragma unroll
        for (int nt = 0; nt < 4; ++nt) {
            int oc = nt * 16 + l15;
            float sc_ = bnw[oc] * rb, sh_ = bnb[oc];
#pragma unroll
            for (int s = 0; s < 2; ++s) {
                f32x4 v = acc[s][nt];
#pragma unroll
                for (int r = 0; r < 4; ++r) {
                    int pos = wv * 32 + s * 16 + quad * 4 + r;
                    float val = v[r] * sc_ + sh_;
                    val = val >= 0.f ? val : 0.01f * val;
                    outS[pos * 72 + oc] = f2b(val);
                }
            }
        }
        __syncthreads();
        for (int i = tid; i < 1024; i += 256) {
            int p = i >> 3, cq = i & 7;
            short8 v = *(const short8*)&outS[p * 72 + cq * 8];
            int y = p >> 5, x = p & 31;
            *(short8*)&goutS[((size_t)(bb * NTOK + z0 * 1024 + (y0 + y) * 32 + x)) * 64 + cq * 8] = v;
        }
    } else {
        short* a2_s = wl_s;            // [128 pos][72 pad] bf16 (9216 shorts)
        short* w8_s = wl_s + 9216;     // [64 out][80 pad] bf16 (5120 shorts)
        f32x4 skr[2][4];
        // direct: bn+skip+lrelu from accumulators -> a2_s (pos = wv*32+s*16+quad*4+r)
#pragma unroll
        for (int nt = 0; nt < 4; ++nt) {
            int oc = nt * 16 + l15;
            float sc_ = bnw[oc] * rb, sh_ = bnb[oc];
#pragma unroll
            for (int s = 0; s < 2; ++s) {
                size_t g = (((size_t)(bb * 64 + oc)) << 15) +
                           ((z0 * 32 + y0 + wv) * 32 + s * 16 + quad * 4);
                f32x4 sk = *(const f32x4*)&skip[g];
                skr[s][nt] = sk;
                f32x4 v = acc[s][nt];
#pragma unroll
                for (int r = 0; r < 4; ++r) {
                    int pos = wv * 32 + s * 16 + quad * 4 + r;
                    float val = v[r] * sc_ + sh_ + sk[r];
                    val = val >= 0.f ? val : 0.01f * val;
                    a2_s[pos * 72 + oc] = f2b(val);
                }
            }
        }
        // stage w8 bf16 [64 out][80 pad]
        for (int i = tid; i < 512; i += 256) {
            int ocw = i >> 3, cq = i & 7;
            *(short8*)&w8_s[ocw * 80 + cq * 8] = *(const short8*)&wb8[ocw * 64 + cq * 8];
        }
        __syncthreads();
        f32x4 acc2[2][4];
#pragma unroll
        for (int s = 0; s < 2; ++s)
#pragma unroll
            for (int nt = 0; nt < 4; ++nt) acc2[s][nt] = (f32x4){0.f, 0.f, 0.f, 0.f};
#pragma unroll
        for (int ks = 0; ks < 2; ++ks) {
            short8 a8[2], b8f[4];
#pragma unroll
            for (int s = 0; s < 2; ++s)
                a8[s] = *(const short8*)&a2_s[(wv * 32 + s * 16 + l15) * 72 + quad * 8 + ks * 32];
#pragma unroll
            for (int nt = 0; nt < 4; ++nt)
                b8f[nt] = *(const short8*)&w8_s[(nt * 16 + l15) * 80 + quad * 8 + ks * 32];
#pragma unroll
            for (int s = 0; s < 2; ++s)
#pragma unroll
                for (int nt = 0; nt < 4; ++nt)
                    acc2[s][nt] = __builtin_amdgcn_mfma_f32_16x16x32_bf16(a8[s], b8f[nt], acc2[s][nt], 0, 0, 0);
        }
        // direct io write from acc2 (same pos->(y=wv, x) mapping), fused skip+bias
#pragma unroll
        for (int nt = 0; nt < 4; ++nt) {
            int oc = nt * 16 + l15;
            float bias8 = b8[oc];
#pragma unroll
            for (int s = 0; s < 2; ++s) {
                size_t g = (((size_t)(bb * 64 + oc)) << 15) +
                           ((z0 * 32 + y0 + wv) * 32 + s * 16 + quad * 4);
                f32x4 o;
#pragma unroll
                for (int r = 0; r < 4; ++r) o[r] = skr[s][nt][r] + acc2[s][nt][r] + bias8;
                *(f32x4*)&io[g] = o;
            }
        }
    }
}

extern "C" void kernel_launch(void* const* d_in, const int* in_sizes, int n_in,
                              void* d_out, int out_size, void* d_ws, size_t ws_size,
                              hipStream_t stream) {
    const float* x      = (const float*)d_in[0];
    const float* ln_w   = (const float*)d_in[1];
    const float* ln_b   = (const float*)d_in[2];
    const float* gamma  = (const float*)d_in[3];
    const float* temp1  = (const float*)d_in[4];
    const float* temp2  = (const float*)d_in[5];
    const float* W_qkvv = (const float*)d_in[6];
    const float* W_EF   = (const float*)d_in[7];
    const float* b_EF   = (const float*)d_in[8];
    const float* W_o1   = (const float*)d_in[9];
    const float* b_o1   = (const float*)d_in[10];
    const float* W_o2   = (const float*)d_in[11];
    const float* b_o2   = (const float*)d_in[12];
    const float* conv1w = (const float*)d_in[13];
    const float* conv2w = (const float*)d_in[14];
    const float* bn1_w  = (const float*)d_in[15];
    const float* bn1_b  = (const float*)d_in[16];
    const float* bn2_w  = (const float*)d_in[17];
    const float* bn2_b  = (const float*)d_in[18];
    const float* conv8w = (const float*)d_in[19];
    const float* conv8b = (const float*)d_in[20];

    // qkvvb = 512 rows x 32768 = 16,777,216 shorts (32 MB); all else after it.
    short* qkvvb = (short*)d_ws;                 // [0, 16777216) shorts
    float* kp    = (float*)(qkvvb + 16777216);   // 8192 floats
    float* vp    = kp + 8192;                    // 8192
    float* qd    = vp + 8192;                    // 2048
    float* qn_acc= qd + 2048;                    // 128
    float* kn_acc= qn_acc + 128;                 // 128
    float* a_ca  = kn_acc + 128;                 // 2048 (unused)
    float* iqn   = a_ca + 2048;                  // 128  (unused)
    float* ikn   = iqn + 128;                    // 128  (unused)
    short* xcab  = (short*)(ikn + 128);          // 4194304 shorts
    short* xsab  = xcab + 4194304;               // 4194304
    short* gA    = xsab + 4194304;               // 4194304
    short* g1    = gA + 4194304;                 // 4194304
    short* wb1   = g1 + 4194304;                 // 110592
    short* wb2   = wb1 + 110592;                 // 110592
    short* wb8   = wb2 + 110592;                 // 4096
    short* wefb  = wb8 + 4096;                   // 2097152
    short* wqb   = wefb + 2097152;               // 16384

    float* attn_skip = (float*)d_out;

    hipLaunchKernelGGL(k_repack, dim3(9177), dim3(256), 0, stream,
                       conv1w, conv2w, conv8w, W_EF, W_qkvv, b_EF,
                       wb1, wb2, wb8, wefb, wqb, kp, vp, qd);
    hipLaunchKernelGGL(k_ln_qkvv, dim3(1024), dim3(256), 0, stream,
                       x, ln_w, ln_b, wqb, qkvvb);
    hipLaunchKernelGGL(k_pq, dim3(32, 8), dim3(256), 0, stream,
                       qkvvb, wefb, kp, vp, qd, qn_acc, kn_acc);
    hipLaunchKernelGGL(k_attn, dim3(128, 8), dim3(256), 0, stream,
                       qkvvb, qd, qn_acc, kn_acc, temp1, kp, vp, temp2, xsab, xcab);
    hipLaunchKernelGGL(k_epilogue, dim3(256), dim3(256), 0, stream,
                       x, xsab, xcab, W_o1, b_o1, W_o2, b_o2, gamma, attn_skip, gA);
    hipLaunchKernelGGL((k_conv3m<0>), dim3(512), dim3(256), 0, stream,
                       gA, wb1, bn1_w, bn1_b, (const float*)nullptr, g1,
                       (const short*)nullptr, (const float*)nullptr, (float*)nullptr);
    hipLaunchKernelGGL((k_conv3m<1>), dim3(512), dim3(256), 0, stream,
                       g1, wb2, bn2_w, bn2_b, attn_skip, (short*)nullptr,
                       wb8, conv8b, attn_skip);
}

// Round 10
// 212.157 us; speedup vs baseline: 1.0757x; 1.0757x over previous
//
#include <hip/hip_runtime.h>

#define NTOK 32768

typedef __attribute__((ext_vector_type(8))) short short8;
typedef __attribute__((ext_vector_type(4))) short short4_t;
typedef __attribute__((ext_vector_type(4))) float f32x4;

__device__ __forceinline__ short f2b(float f) {
    union { float f; unsigned u; } v; v.f = f;
    unsigned r = v.u + 0x7fffu + ((v.u >> 16) & 1u);
    return (short)(r >> 16);
}
__device__ __forceinline__ float b2f(short s) {
    union { float f; unsigned u; } v;
    v.u = ((unsigned)(unsigned short)s) << 16;
    return v.f;
}

// ------- setup: repack conv weights, bf16 conversions, init accumulators -------
__global__ void k_repack(const float* __restrict__ w1, const float* __restrict__ w2,
                         const float* __restrict__ w8, const float* __restrict__ wef,
                         const float* __restrict__ wq, const float* __restrict__ bEF,
                         short* __restrict__ wb1, short* __restrict__ wb2,
                         short* __restrict__ wb8, short* __restrict__ wefb,
                         short* __restrict__ wqb, float* __restrict__ kp,
                         float* __restrict__ vp, float* __restrict__ qd)
{
    int i = blockIdx.x * 256 + threadIdx.x;
    if (i >= 2349312) return;
    if (i >= 2347008) { qd[i - 2347008] = 0.f; return; }
    if (i >= 2338816) {
        int j = i - 2338816;
        float v = bEF[j & 63];
        kp[j] = v; vp[j] = v; return;
    }
    if (i >= 2322432) { int j = i - 2322432; wqb[j] = f2b(wq[j]); return; }
    if (i >= 225280)  { int j = i - 225280;  wefb[j] = f2b(wef[j]); return; }
    if (i >= 221184)  { int j = i - 221184;  wb8[j] = f2b(w8[j]); return; }
    int sel = i >= 110592;
    int j = sel ? i - 110592 : i;
    int tap = j >> 12;
    int r = j & 4095;
    int oc = r >> 6, ic = r & 63;
    const float* w = sel ? w2 : w1;
    short* o = sel ? wb2 : wb1;
    o[j] = f2b(w[(oc * 64 + ic) * 27 + tap]);
}

// ---------------- fused LayerNorm + QKVV GEMM (MFMA), bf16 W ----------------
// qkvvb layout: bf16 [isel(4)][b(2)][h(4)][d(16)][N]  (512 rows x 32768 = 32 MB)
__global__ __launch_bounds__(256) void k_ln_qkvv(
    const float* __restrict__ x, const float* __restrict__ lnw,
    const float* __restrict__ lnb, const short* __restrict__ wqb,
    short* __restrict__ qkvvb)
{
    __shared__ __align__(16) short Wl[256 * 72];
    __shared__ __align__(16) short tr[256 * 72];
    __shared__ float red1[4][64], red2[4][64];
    __shared__ float mu_s[64], rs_s[64];
    short* al = tr;                                 // bf16 [64 t][72]

    int bid = blockIdx.x;
    int b = bid >> 9;
    int n0 = (bid & 511) << 6;
    int tid = threadIdx.x;

    for (int i = tid; i < 2048; i += 256) {
        int out = i >> 3, q8 = (i & 7) * 8;
        *(short8*)&Wl[out * 72 + q8] = *(const short8*)&wqb[out * 64 + q8];
    }

    int t = tid & 63, cq = tid >> 6;
    float xr[16];
    float s1 = 0.f, s2 = 0.f;
    const float* xb = x + (((size_t)(b * 64 + cq * 16)) << 15) + n0 + t;
#pragma unroll
    for (int j = 0; j < 16; ++j) {
        float v = xb[(size_t)j << 15];
        xr[j] = v; s1 += v; s2 += v * v;
    }
    red1[cq][t] = s1; red2[cq][t] = s2;
    __syncthreads();
    if (tid < 64) {
        float a = red1[0][tid] + red1[1][tid] + red1[2][tid] + red1[3][tid];
        float q = red2[0][tid] + red2[1][tid] + red2[2][tid] + red2[3][tid];
        float mu = a * (1.f / 64.f);
        float var = q * (1.f / 64.f) - mu * mu;
        mu_s[tid] = mu;
        rs_s[tid] = rsqrtf(var + 1e-5f);
    }
    __syncthreads();
    {
        float mu = mu_s[t], rs = rs_s[t];
        short8 p0, p1;
#pragma unroll
        for (int j = 0; j < 8; ++j) {
            int c = cq * 16 + j;
            p0[j] = f2b((xr[j] - mu) * rs * lnw[c] + lnb[c]);
        }
#pragma unroll
        for (int j = 0; j < 8; ++j) {
            int c = cq * 16 + 8 + j;
            p1[j] = f2b((xr[8 + j] - mu) * rs * lnw[c] + lnb[c]);
        }
        *(short8*)&al[t * 72 + cq * 16] = p0;
        *(short8*)&al[t * 72 + cq * 16 + 8] = p1;
    }
    __syncthreads();

    int w = tid >> 6, lane = tid & 63, l15 = lane & 15, quad = lane >> 4;
    f32x4 acc[4][4];
#pragma unroll
    for (int mt = 0; mt < 4; ++mt)
#pragma unroll
        for (int nt = 0; nt < 4; ++nt) acc[mt][nt] = (f32x4){0.f, 0.f, 0.f, 0.f};
#pragma unroll
    for (int ks = 0; ks < 2; ++ks) {
        short8 af[4], bf[4];
#pragma unroll
        for (int mt = 0; mt < 4; ++mt)
            af[mt] = *(const short8*)&al[(mt * 16 + l15) * 72 + quad * 8 + ks * 32];
#pragma unroll
        for (int nt = 0; nt < 4; ++nt)
            bf[nt] = *(const short8*)&Wl[(w * 64 + nt * 16 + l15) * 72 + quad * 8 + ks * 32];
#pragma unroll
        for (int mt = 0; mt < 4; ++mt)
#pragma unroll
            for (int nt = 0; nt < 4; ++nt)
                acc[mt][nt] = __builtin_amdgcn_mfma_f32_16x16x32_bf16(af[mt], bf[nt], acc[mt][nt], 0, 0, 0);
    }
    __syncthreads();

#pragma unroll
    for (int mt = 0; mt < 4; ++mt)
#pragma unroll
        for (int nt = 0; nt < 4; ++nt) {
            int out = w * 64 + nt * 16 + l15;
            short4_t sv;
#pragma unroll
            for (int r = 0; r < 4; ++r) sv[r] = f2b(acc[mt][nt][r]);
            *(short4_t*)&tr[out * 72 + mt * 16 + quad * 4] = sv;
        }
    __syncthreads();
    for (int i = tid; i < 2048; i += 256) {
        int o = i >> 3, tq = (i & 7) * 8;
        short8 v = *(const short8*)&tr[o * 72 + tq];
        int isel = o >> 6, h = (o >> 4) & 3, d = o & 15;
        *(short8*)&qkvvb[((size_t)(((isel * 2 + b) * 4 + h) * 16 + d) << 15) + n0 + tq] = v;
    }
}

// ------- merged MFMA: k/v projections + q.k logits + L2-norm accumulators -------
// (round-8 proven version: 32-way split, scattered reads; the round-9 LDS-staged
// variant regressed +12us — reverted.)
__global__ __launch_bounds__(256) void k_pq(
    const short* __restrict__ qkvvb, const short* __restrict__ wefb,
    float* __restrict__ kp, float* __restrict__ vp, float* __restrict__ qd,
    float* __restrict__ qn_acc, float* __restrict__ kn_acc)
{
    __shared__ float redb[3][64][38];
    int kc = blockIdx.x, bh = blockIdx.y;
    int tid = threadIdx.x;
    int w = tid >> 6, lane = tid & 63, l15 = lane & 15, quad = lane >> 4;
    size_t qrow = ((size_t)(bh * 16 + l15)) << 15;
    size_t krow = ((size_t)(128 + bh * 16 + l15)) << 15;
    size_t vrow = ((size_t)(384 + bh * 16 + l15)) << 15;
    int nbase = kc * 1024 + w * 256 + quad * 8;
    f32x4 acck[4], accv[4], accqd, accqq, acckk;
#pragma unroll
    for (int nt = 0; nt < 4; ++nt) {
        acck[nt] = (f32x4){0.f, 0.f, 0.f, 0.f};
        accv[nt] = (f32x4){0.f, 0.f, 0.f, 0.f};
    }
    accqd = (f32x4){0.f, 0.f, 0.f, 0.f};
    accqq = (f32x4){0.f, 0.f, 0.f, 0.f};
    acckk = (f32x4){0.f, 0.f, 0.f, 0.f};
#pragma unroll
    for (int ks = 0; ks < 8; ++ks) {
        int n = nbase + ks * 32;
        short8 qf = *(const short8*)&qkvvb[qrow + n];
        short8 kf = *(const short8*)&qkvvb[krow + n];
        short8 vf = *(const short8*)&qkvvb[vrow + n];
        accqd = __builtin_amdgcn_mfma_f32_16x16x32_bf16(qf, kf, accqd, 0, 0, 0);
        accqq = __builtin_amdgcn_mfma_f32_16x16x32_bf16(qf, qf, accqq, 0, 0, 0);
        acckk = __builtin_amdgcn_mfma_f32_16x16x32_bf16(kf, kf, acckk, 0, 0, 0);
#pragma unroll
        for (int nt = 0; nt < 4; ++nt) {
            short8 wf = *(const short8*)&wefb[(((size_t)(nt * 16 + l15)) << 15) + n];
            acck[nt] = __builtin_amdgcn_mfma_f32_16x16x32_bf16(kf, wf, acck[nt], 0, 0, 0);
            accv[nt] = __builtin_amdgcn_mfma_f32_16x16x32_bf16(vf, wf, accv[nt], 0, 0, 0);
        }
    }
    int diag = (quad == (l15 >> 2));
    float qqv = diag ? accqq[l15 & 3] : 0.f;
    float kkv = diag ? acckk[l15 & 3] : 0.f;
    if (w > 0) {
        float* p = &redb[w - 1][lane][0];
#pragma unroll
        for (int nt = 0; nt < 4; ++nt)
#pragma unroll
            for (int r = 0; r < 4; ++r) { p[nt * 4 + r] = acck[nt][r]; p[16 + nt * 4 + r] = accv[nt][r]; }
#pragma unroll
        for (int r = 0; r < 4; ++r) p[32 + r] = accqd[r];
        p[36] = qqv; p[37] = kkv;
    }
    __syncthreads();
    if (w == 0) {
#pragma unroll
        for (int wv = 0; wv < 3; ++wv) {
            const float* p = &redb[wv][lane][0];
#pragma unroll
            for (int nt = 0; nt < 4; ++nt)
#pragma unroll
                for (int r = 0; r < 4; ++r) { acck[nt][r] += p[nt * 4 + r]; accv[nt][r] += p[16 + nt * 4 + r]; }
#pragma unroll
            for (int r = 0; r < 4; ++r) accqd[r] += p[32 + r];
            qqv += p[36]; kkv += p[37];
        }
        int d = quad * 4;
#pragma unroll
        for (int nt = 0; nt < 4; ++nt)
#pragma unroll
            for (int r = 0; r < 4; ++r) {
                int idx = (bh * 16 + d + r) * 64 + nt * 16 + l15;
                atomicAdd(&kp[idx], acck[nt][r]);
                atomicAdd(&vp[idx], accv[nt][r]);
            }
#pragma unroll
        for (int r = 0; r < 4; ++r)
            atomicAdd(&qd[bh * 256 + (d + r) * 16 + l15], accqd[r]);
        if (diag) {
            atomicAdd(&qn_acc[bh * 16 + l15], qqv);
            atomicAdd(&kn_acc[bh * 16 + l15], kkv);
        }
    }
}

// ---------------- fused x_ca + spatial attention — MFMA, fused softmax->PV ----------------
// Round-10: Pl shrunk 4x64x72 -> 4x16x72 (36KB -> 9KB) by fusing softmax and PV
// per 16-token tile: PV tile mt consumes exactly the rows softmax iteration
// tnt==mt produces, and wave-internal LDS write->read needs no barrier.
// Block LDS 55.8KB -> 27.8KB: occupancy 2 -> 5 blocks/CU (VGPR-88 cap = 5 w/SIMD)
// for this latency-bound kernel (measured r9: 44.4us, MfmaUtil 1.4, Occ 19%).
__global__ __launch_bounds__(256) void k_attn(
    const short* __restrict__ qkvvb, const float* __restrict__ qd,
    const float* __restrict__ qn_acc, const float* __restrict__ kn_acc,
    const float* __restrict__ temp1, const float* __restrict__ kp,
    const float* __restrict__ vp, const float* __restrict__ temp2,
    short* __restrict__ xsab, short* __restrict__ xcab)
{
    __shared__ float kl[16][68];
    __shared__ float vl[16][68];
    __shared__ float alca[16][17];
    __shared__ float iqs[16], iks[16];
    __shared__ __align__(16) short Pl[4][16][72];   // per-wave 16-token P tile, XOR-swizzled cols
    __shared__ short Ol[4][64][17];                 // per-wave O transpose staging
    int bh = blockIdx.y; int b = bh >> 2, h = bh & 3;
    int tid = threadIdx.x;
    for (int i = tid; i < 1024; i += 256) {
        kl[i >> 6][i & 63] = kp[bh * 1024 + i];
        vl[i >> 6][i & 63] = vp[bh * 1024 + i];
    }
    if (tid < 32) {
        int j = tid & 15;
        float v = (tid < 16) ? qn_acc[bh * 16 + j] : kn_acc[bh * 16 + j];
        float rv = 1.f / fmaxf(sqrtf(v), 1e-12f);
        if (tid < 16) iqs[j] = rv; else iks[j] = rv;
    }
    __syncthreads();
    {   // CA softmax: row r = tid>>4 (lanes r*16..r*16+15 contiguous in-wave)
        int r = tid >> 4, e = tid & 15;
        float v = qd[bh * 256 + tid] * iqs[r] * iks[e] * temp1[h];
        float mx = v;
#pragma unroll
        for (int m = 1; m < 16; m <<= 1) mx = fmaxf(mx, __shfl_xor(mx, m));
        float ex = __expf(v - mx);
        float s = ex;
#pragma unroll
        for (int m = 1; m < 16; m <<= 1) s += __shfl_xor(s, m);
        alca[r][e] = ex / s;
    }
    __syncthreads();

    int w = tid >> 6, lane = tid & 63, l15 = lane & 15, quad = lane >> 4;
    int tw = (blockIdx.x << 8) + w * 64;
    float t2 = temp2[h];
    const short8 zero8 = {0, 0, 0, 0, 0, 0, 0, 0};
    int xs = (l15 & 7) << 3;                        // Pl bank swizzle (per token row)

    // ---- B-frags: Qn[tok][d] (k = d, zero-padded 16..31) ----
    short8 qb[4];
    if (quad < 2) {
#pragma unroll
        for (int tnt = 0; tnt < 4; ++tnt) {
            short8 v;
#pragma unroll
            for (int j = 0; j < 8; ++j) {
                int d = quad * 8 + j;
                short qv = qkvvb[(((size_t)(bh * 16 + d)) << 15) + tw + tnt * 16 + l15];
                v[j] = f2b(b2f(qv) * iqs[d]);
            }
            qb[tnt] = v;
        }
    } else {
#pragma unroll
        for (int tnt = 0; tnt < 4; ++tnt) qb[tnt] = zero8;
    }
    // ---- A-frags: Kp[p][d] from kl ----
    short8 ka[4];
    if (quad < 2) {
#pragma unroll
        for (int pmt = 0; pmt < 4; ++pmt) {
            short8 v;
#pragma unroll
            for (int j = 0; j < 8; ++j) v[j] = f2b(kl[quad * 8 + j][pmt * 16 + l15]);
            ka[pmt] = v;
        }
    } else {
#pragma unroll
        for (int pmt = 0; pmt < 4; ++pmt) ka[pmt] = zero8;
    }

    // ---- S^T = Kp . Qn^T : 16 MFMAs ----
    f32x4 st[4][4];
#pragma unroll
    for (int pmt = 0; pmt < 4; ++pmt)
#pragma unroll
        for (int tnt = 0; tnt < 4; ++tnt) st[pmt][tnt] = (f32x4){0.f, 0.f, 0.f, 0.f};
#pragma unroll
    for (int pmt = 0; pmt < 4; ++pmt)
#pragma unroll
        for (int tnt = 0; tnt < 4; ++tnt)
            st[pmt][tnt] = __builtin_amdgcn_mfma_f32_16x16x32_bf16(ka[pmt], qb[tnt], st[pmt][tnt], 0, 0, 0);

    // ---- Vp B-frags (k = p, full 64) — needed inside the fused loop ----
    short8 vb[2];
#pragma unroll
    for (int ks = 0; ks < 2; ++ks) {
        short8 t;
#pragma unroll
        for (int j = 0; j < 8; ++j) t[j] = f2b(vl[l15][quad * 8 + ks * 32 + j]);
        vb[ks] = t;
    }

    // ---- fused: per 16-token tile, softmax over p -> Pl (rows l15) -> PV MFMA ----
    f32x4 vo[4];
#pragma unroll
    for (int tnt = 0; tnt < 4; ++tnt) {
        float v[16];
        float mx = -1e30f;
#pragma unroll
        for (int pmt = 0; pmt < 4; ++pmt)
#pragma unroll
            for (int r = 0; r < 4; ++r) {
                float x = st[pmt][tnt][r] * t2;
                v[pmt * 4 + r] = x; mx = fmaxf(mx, x);
            }
        mx = fmaxf(mx, __shfl_xor(mx, 16));
        mx = fmaxf(mx, __shfl_xor(mx, 32));
        float s = 0.f;
#pragma unroll
        for (int i2 = 0; i2 < 16; ++i2) { v[i2] = __expf(v[i2] - mx); s += v[i2]; }
        s += __shfl_xor(s, 16);
        s += __shfl_xor(s, 32);
        float inv = 1.f / s;
#pragma unroll
        for (int pmt = 0; pmt < 4; ++pmt)
#pragma unroll
            for (int t = 0; t < 2; ++t) {
                unsigned lo = (unsigned short)f2b(v[pmt * 4 + 2 * t] * inv);
                unsigned hi = (unsigned short)f2b(v[pmt * 4 + 2 * t + 1] * inv);
                int col = (pmt * 16 + quad * 4 + 2 * t) ^ xs;
                *(unsigned*)&Pl[w][l15][col] = lo | (hi << 16);
            }
        // wave-internal write->read: compiler inserts lgkmcnt; no barrier needed
        vo[tnt] = (f32x4){0.f, 0.f, 0.f, 0.f};
#pragma unroll
        for (int ks = 0; ks < 2; ++ks) {
            short8 pa = *(const short8*)&Pl[w][l15][(quad * 8 + ks * 32) ^ xs];
            vo[tnt] = __builtin_amdgcn_mfma_f32_16x16x32_bf16(pa, vb[ks], vo[tnt], 0, 0, 0);
        }
    }

    // ---- CA: x_ca = Vca . alca^T (k = e, zero-padded 16..31) ----
    short8 ab[4], bb;
    if (quad < 2) {
        short8 t;
#pragma unroll
        for (int j = 0; j < 8; ++j) t[j] = f2b(alca[l15][quad * 8 + j]);
        bb = t;
#pragma unroll
        for (int mt = 0; mt < 4; ++mt) {
            short8 u;
#pragma unroll
            for (int j = 0; j < 8; ++j)
                u[j] = qkvvb[(((size_t)(256 + bh * 16 + quad * 8 + j)) << 15) + tw + mt * 16 + l15];
            ab[mt] = u;
        }
    } else {
        bb = zero8;
#pragma unroll
        for (int mt = 0; mt < 4; ++mt) ab[mt] = zero8;
    }
    f32x4 ca[4];
#pragma unroll
    for (int mt = 0; mt < 4; ++mt) ca[mt] = (f32x4){0.f, 0.f, 0.f, 0.f};
#pragma unroll
    for (int mt = 0; mt < 4; ++mt)
        ca[mt] = __builtin_amdgcn_mfma_f32_16x16x32_bf16(ab[mt], bb, ca[mt], 0, 0, 0);

    // ---- CA direct stores (lane: tok=mt*16+quad*4+r, d=l15; 32B-coalesced) ----
#pragma unroll
    for (int mt = 0; mt < 4; ++mt)
#pragma unroll
        for (int r = 0; r < 4; ++r) {
            int tok = tw + mt * 16 + quad * 4 + r;
            xcab[((size_t)(b * NTOK + tok)) * 64 + h * 16 + l15] = f2b(ca[mt][r]);
        }

    // ---- O via LDS transpose -> token-coalesced xsab writes ----
#pragma unroll
    for (int mt = 0; mt < 4; ++mt)
#pragma unroll
        for (int r = 0; r < 4; ++r)
            Ol[w][mt * 16 + quad * 4 + r][l15] = f2b(vo[mt][r]);
#pragma unroll
    for (int d = 0; d < 16; ++d) {
        short vv = Ol[w][lane][d];
        xsab[(size_t)b * 2097152 + (((size_t)(d * 4 + h)) << 15) + tw + lane] = vv;
    }
}

// ---------------- EPA epilogue (MFMA): proj + gamma + residual ----------------
__global__ __launch_bounds__(256) void k_epilogue(
    const float* __restrict__ x, const short* __restrict__ xsab,
    const short* __restrict__ xcab, const float* __restrict__ Wo1,
    const float* __restrict__ bo1, const float* __restrict__ Wo2,
    const float* __restrict__ bo2, const float* __restrict__ gamma,
    float* __restrict__ attn_skip, short* __restrict__ gA)
{
    __shared__ __align__(16) short Wl[64 * 72];    // rows 0-31: Wo1, 32-63: Wo2 (bf16)
    __shared__ __align__(16) short trS[256 * 72];  // bf16 [256 tok][72] for gA transpose
    int tid = threadIdx.x;
    int bidx = blockIdx.x;
    int b = bidx >> 7;
    int n0 = (bidx & 127) << 8;                    // 256 tokens per block
    for (int i = tid; i < 4096; i += 256) {
        int row = i >> 6, c = i & 63;
        float wv = (row < 32) ? Wo1[row * 64 + c] : Wo2[(row - 32) * 64 + c];
        Wl[row * 72 + c] = f2b(wv);
    }
    __syncthreads();

    int w = tid >> 6, lane = tid & 63, l15 = lane & 15, quad = lane >> 4;
    int tw = n0 + w * 64;
    const short* sa_base = xsab + (size_t)b * 2097152;
    const short* ca_base = xcab + (size_t)b * 2097152;

    f32x4 acc_sa[4][2], acc_ca[4][2];
#pragma unroll
    for (int mt = 0; mt < 4; ++mt)
#pragma unroll
        for (int nt = 0; nt < 2; ++nt) {
            acc_sa[mt][nt] = (f32x4){0.f, 0.f, 0.f, 0.f};
            acc_ca[mt][nt] = (f32x4){0.f, 0.f, 0.f, 0.f};
        }
#pragma unroll
    for (int ks = 0; ks < 2; ++ks) {
        int ko = quad * 8 + ks * 32;
        short8 b1[2], b2[2];
#pragma unroll
        for (int nt = 0; nt < 2; ++nt) {
            b1[nt] = *(const short8*)&Wl[(nt * 16 + l15) * 72 + ko];
            b2[nt] = *(const short8*)&Wl[(32 + nt * 16 + l15) * 72 + ko];
        }
#pragma unroll
        for (int mt = 0; mt < 4; ++mt) {
            int trow = tw + mt * 16 + l15;
            short8 a1 = *(const short8*)&sa_base[(size_t)trow * 64 + ko];
            short8 a2 = *(const short8*)&ca_base[(size_t)trow * 64 + ko];
#pragma unroll
            for (int nt = 0; nt < 2; ++nt) {
                acc_sa[mt][nt] = __builtin_amdgcn_mfma_f32_16x16x32_bf16(a1, b1[nt], acc_sa[mt][nt], 0, 0, 0);
                acc_ca[mt][nt] = __builtin_amdgcn_mfma_f32_16x16x32_bf16(a2, b2[nt], acc_ca[mt][nt], 0, 0, 0);
            }
        }
    }

    // fused residual: v = x + gamma*(acc + bias); write attn_skip (f32x4/lane);
    // stash bf16 into trS row=token (one scalar store per token — C rows differ!)
#pragma unroll
    for (int half = 0; half < 2; ++half) {   // 0: sa -> c in [0,32), 1: ca -> c in [32,64)
#pragma unroll
        for (int nt = 0; nt < 2; ++nt) {
            int c = half * 32 + nt * 16 + l15;
            float g = gamma[c];
            float bias = half ? bo2[c - 32] : bo1[c];
#pragma unroll
            for (int mt = 0; mt < 4; ++mt) {
                f32x4 a = half ? acc_ca[mt][nt] : acc_sa[mt][nt];
                int tbase = tw + mt * 16 + quad * 4;
                size_t gidx = (((size_t)(b * 64 + c)) << 15) + tbase;
                f32x4 xv = *(const f32x4*)&x[gidx];
                f32x4 o;
#pragma unroll
                for (int r = 0; r < 4; ++r) {
                    float v = xv[r] + g * (a[r] + bias);
                    o[r] = v;
                    trS[(w * 64 + mt * 16 + quad * 4 + r) * 72 + c] = f2b(v);
                }
                *(f32x4*)&attn_skip[gidx] = o;
            }
        }
    }
    __syncthreads();
    // coalesced NHWC gA write
    for (int i = tid; i < 2048; i += 256) {
        int tok = i >> 3, cq = (i & 7) * 8;
        short8 v = *(const short8*)&trS[tok * 72 + cq];
        *(short8*)&gA[((size_t)(b * NTOK + n0 + tok)) * 64 + cq] = v;
    }
}

// ---------------- MFMA implicit-GEMM 3x3x3 conv (round-8 proven) ----------------
template <int MODE>
__global__ __launch_bounds__(256) void k_conv3m(
    const short* __restrict__ gin, const short* __restrict__ wb,
    const float* __restrict__ bnw, const float* __restrict__ bnb,
    const float* __restrict__ skip, short* __restrict__ goutS,
    const short* __restrict__ wb8, const float* __restrict__ b8,
    float* __restrict__ io)
{
    __shared__ __align__(16) short inl_s[24480];   // [3z][6y][34x][40 icpad]
    __shared__ __align__(16) short wl_s[15360];    // 2 x [3][64][40]; MODE1 epi: a2(9216)+w8[64][80]@9216
    int bx = blockIdx.x;
    int bb = bx >> 8;
    int z0 = (bx >> 3) & 31;
    int y0 = (bx & 7) * 4;
    int tid = threadIdx.x;
    int lane = tid & 63, wv = tid >> 6;
    int l15 = lane & 15, quad = lane >> 4;
    int wo = tid >> 2, wq = tid & 3;

    f32x4 acc[2][4];
#pragma unroll
    for (int s = 0; s < 2; ++s)
#pragma unroll
        for (int nt = 0; nt < 4; ++nt) acc[s][nt] = (f32x4){0.f, 0.f, 0.f, 0.f};

    for (int chunk = 0; chunk < 2; ++chunk) {
        const short* wck = wb + chunk * 32 + wq * 8;
        // prefetch stages 0 AND 1 into regs (2-deep rotation)
        short8 wr[2][3];
#pragma unroll
        for (int t = 0; t < 3; ++t) {
            wr[0][t] = *(const short8*)&wck[(size_t)(t * 64 + wo) * 64];
            wr[1][t] = *(const short8*)&wck[(size_t)((3 + t) * 64 + wo) * 64];
        }
        __syncthreads();   // prev chunk's inl_s reads + wl_s buf reads done
        for (int i = tid; i < 2448; i += 256) {
            int p = i >> 2, icq = i & 3;
            int xi = p % 34; int t2 = p / 34; int yi = t2 % 6; int zi = t2 / 6;
            int gz = z0 + zi - 1, gy = y0 + yi - 1, gx = xi - 1;
            short8 v = {0, 0, 0, 0, 0, 0, 0, 0};
            if ((unsigned)gz < 32u && (unsigned)gy < 32u && (unsigned)gx < 32u)
                v = *(const short8*)&gin[((size_t)(bb * NTOK + gz * 1024 + gy * 32 + gx)) * 64 + chunk * 32 + icq * 8];
            *(short8*)&inl_s[p * 40 + icq * 8] = v;
        }
        // write stage-0 weights to buf0
#pragma unroll
        for (int t = 0; t < 3; ++t)
            *(short8*)&wl_s[(t * 64 + wo) * 40 + wq * 8] = wr[0][t];

#pragma unroll
        for (int kz = 0; kz < 3; ++kz)
#pragma unroll
        for (int ky = 0; ky < 3; ++ky) {
            const int sidx = kz * 3 + ky;
            __syncthreads();   // buf[sidx&1] writes visible; buf[(sidx+1)&1] reads (stage sidx-1) done
            if (sidx < 7) {
                // load stage sidx+2 into the slot just freed (held stage sidx)
#pragma unroll
                for (int t = 0; t < 3; ++t)
                    wr[sidx & 1][t] = *(const short8*)&wck[(size_t)(((sidx + 2) * 3 + t) * 64 + wo) * 64];
            }
            const short* wcur = &wl_s[(sidx & 1) * 7680];
            int rowb = (kz * 6 + wv + ky) * 34;
#pragma unroll
            for (int kx = 0; kx < 3; ++kx) {
                short8 bf[4];
#pragma unroll
                for (int nt = 0; nt < 4; ++nt)
                    bf[nt] = *(const short8*)&wcur[(kx * 64 + nt * 16 + l15) * 40 + quad * 8];
#pragma unroll
                for (int s = 0; s < 2; ++s) {
                    short8 af = *(const short8*)&inl_s[(rowb + s * 16 + l15 + kx) * 40 + quad * 8];
#pragma unroll
                    for (int nt = 0; nt < 4; ++nt)
                        acc[s][nt] = __builtin_amdgcn_mfma_f32_16x16x32_bf16(af, bf[nt], acc[s][nt], 0, 0, 0);
                }
            }
            if (sidx < 8) {
                // write stage sidx+1 (loaded at stage sidx-1 -> fully landed)
                short* wnext = &wl_s[((sidx + 1) & 1) * 7680];
#pragma unroll
                for (int t = 0; t < 3; ++t)
                    *(short8*)&wnext[(t * 64 + wo) * 40 + wq * 8] = wr[(sidx + 1) & 1][t];
            }
        }
    }
    __syncthreads();
    float rb = rsqrtf(1.f + 1e-5f);
    if (MODE == 0) {
        short* outS = inl_s;  // [128 pos][72 pad] bf16
#pragma unroll
        for (int nt = 0; nt < 4; ++nt) {
            int oc = nt * 16 + l15;
            float sc_ = bnw[oc] * rb, sh_ = bnb[oc];
#pragma unroll
            for (int s = 0; s < 2; ++s) {
                f32x4 v = acc[s][nt];
#pragma unroll
                for (int r = 0; r < 4; ++r) {
                    int pos = wv * 32 + s * 16 + quad * 4 + r;
                    float val = v[r] * sc_ + sh_;
                    val = val >= 0.f ? val : 0.01f * val;
                    outS[pos * 72 + oc] = f2b(val);
                }
            }
        }
        __syncthreads();
        for (int i = tid; i < 1024; i += 256) {
            int p = i >> 3, cq = i & 7;
            short8 v = *(const short8*)&outS[p * 72 + cq * 8];
            int y = p >> 5, x = p & 31;
            *(short8*)&goutS[((size_t)(bb * NTOK + z0 * 1024 + (y0 + y) * 32 + x)) * 64 + cq * 8] = v;
        }
    } else {
        short* a2_s = wl_s;            // [128 pos][72 pad] bf16 (9216 shorts)
        short* w8_s = wl_s + 9216;     // [64 out][80 pad] bf16 (5120 shorts)
        f32x4 skr[2][4];
        // direct: bn+skip+lrelu from accumulators -> a2_s (pos = wv*32+s*16+quad*4+r)
#pragma unroll
        for (int nt = 0; nt < 4; ++nt) {
            int oc = nt * 16 + l15;
            float sc_ = bnw[oc] * rb, sh_ = bnb[oc];
#pragma unroll
            for (int s = 0; s < 2; ++s) {
                size_t g = (((size_t)(bb * 64 + oc)) << 15) +
                           ((z0 * 32 + y0 + wv) * 32 + s * 16 + quad * 4);
                f32x4 sk = *(const f32x4*)&skip[g];
                skr[s][nt] = sk;
                f32x4 v = acc[s][nt];
#pragma unroll
                for (int r = 0; r < 4; ++r) {
                    int pos = wv * 32 + s * 16 + quad * 4 + r;
                    float val = v[r] * sc_ + sh_ + sk[r];
                    val = val >= 0.f ? val : 0.01f * val;
                    a2_s[pos * 72 + oc] = f2b(val);
                }
            }
        }
        // stage w8 bf16 [64 out][80 pad]
        for (int i = tid; i < 512; i += 256) {
            int ocw = i >> 3, cq = i & 7;
            *(short8*)&w8_s[ocw * 80 + cq * 8] = *(const short8*)&wb8[ocw * 64 + cq * 8];
        }
        __syncthreads();
        f32x4 acc2[2][4];
#pragma unroll
        for (int s = 0; s < 2; ++s)
#pragma unroll
            for (int nt = 0; nt < 4; ++nt) acc2[s][nt] = (f32x4){0.f, 0.f, 0.f, 0.f};
#pragma unroll
        for (int ks = 0; ks < 2; ++ks) {
            short8 a8[2], b8f[4];
#pragma unroll
            for (int s = 0; s < 2; ++s)
                a8[s] = *(const short8*)&a2_s[(wv * 32 + s * 16 + l15) * 72 + quad * 8 + ks * 32];
#pragma unroll
            for (int nt = 0; nt < 4; ++nt)
                b8f[nt] = *(const short8*)&w8_s[(nt * 16 + l15) * 80 + quad * 8 + ks * 32];
#pragma unroll
            for (int s = 0; s < 2; ++s)
#pragma unroll
                for (int nt = 0; nt < 4; ++nt)
                    acc2[s][nt] = __builtin_amdgcn_mfma_f32_16x16x32_bf16(a8[s], b8f[nt], acc2[s][nt], 0, 0, 0);
        }
        // direct io write from acc2 (same pos->(y=wv, x) mapping), fused skip+bias
#pragma unroll
        for (int nt = 0; nt < 4; ++nt) {
            int oc = nt * 16 + l15;
            float bias8 = b8[oc];
#pragma unroll
            for (int s = 0; s < 2; ++s) {
                size_t g = (((size_t)(bb * 64 + oc)) << 15) +
                           ((z0 * 32 + y0 + wv) * 32 + s * 16 + quad * 4);
                f32x4 o;
#pragma unroll
                for (int r = 0; r < 4; ++r) o[r] = skr[s][nt][r] + acc2[s][nt][r] + bias8;
                *(f32x4*)&io[g] = o;
            }
        }
    }
}

extern "C" void kernel_launch(void* const* d_in, const int* in_sizes, int n_in,
                              void* d_out, int out_size, void* d_ws, size_t ws_size,
                              hipStream_t stream) {
    const float* x      = (const float*)d_in[0];
    const float* ln_w   = (const float*)d_in[1];
    const float* ln_b   = (const float*)d_in[2];
    const float* gamma  = (const float*)d_in[3];
    const float* temp1  = (const float*)d_in[4];
    const float* temp2  = (const float*)d_in[5];
    const float* W_qkvv = (const float*)d_in[6];
    const float* W_EF   = (const float*)d_in[7];
    const float* b_EF   = (const float*)d_in[8];
    const float* W_o1   = (const float*)d_in[9];
    const float* b_o1   = (const float*)d_in[10];
    const float* W_o2   = (const float*)d_in[11];
    const float* b_o2   = (const float*)d_in[12];
    const float* conv1w = (const float*)d_in[13];
    const float* conv2w = (const float*)d_in[14];
    const float* bn1_w  = (const float*)d_in[15];
    const float* bn1_b  = (const float*)d_in[16];
    const float* bn2_w  = (const float*)d_in[17];
    const float* bn2_b  = (const float*)d_in[18];
    const float* conv8w = (const float*)d_in[19];
    const float* conv8b = (const float*)d_in[20];

    // qkvvb = 512 rows x 32768 = 16,777,216 shorts (32 MB); all else after it.
    short* qkvvb = (short*)d_ws;                 // [0, 16777216) shorts
    float* kp    = (float*)(qkvvb + 16777216);   // 8192 floats
    float* vp    = kp + 8192;                    // 8192
    float* qd    = vp + 8192;                    // 2048
    float* qn_acc= qd + 2048;                    // 128
    float* kn_acc= qn_acc + 128;                 // 128
    float* a_ca  = kn_acc + 128;                 // 2048 (unused)
    float* iqn   = a_ca + 2048;                  // 128  (unused)
    float* ikn   = iqn + 128;                    // 128  (unused)
    short* xcab  = (short*)(ikn + 128);          // 4194304 shorts
    short* xsab  = xcab + 4194304;               // 4194304
    short* gA    = xsab + 4194304;               // 4194304
    short* g1    = gA + 4194304;                 // 4194304
    short* wb1   = g1 + 4194304;                 // 110592
    short* wb2   = wb1 + 110592;                 // 110592
    short* wb8   = wb2 + 110592;                 // 4096
    short* wefb  = wb8 + 4096;                   // 2097152
    short* wqb   = wefb + 2097152;               // 16384

    float* attn_skip = (float*)d_out;

    hipLaunchKernelGGL(k_repack, dim3(9177), dim3(256), 0, stream,
                       conv1w, conv2w, conv8w, W_EF, W_qkvv, b_EF,
                       wb1, wb2, wb8, wefb, wqb, kp, vp, qd);
    hipLaunchKernelGGL(k_ln_qkvv, dim3(1024), dim3(256), 0, stream,
                       x, ln_w, ln_b, wqb, qkvvb);
    hipLaunchKernelGGL(k_pq, dim3(32, 8), dim3(256), 0, stream,
                       qkvvb, wefb, kp, vp, qd, qn_acc, kn_acc);
    hipLaunchKernelGGL(k_attn, dim3(128, 8), dim3(256), 0, stream,
                       qkvvb, qd, qn_acc, kn_acc, temp1, kp, vp, temp2, xsab, xcab);
    hipLaunchKernelGGL(k_epilogue, dim3(256), dim3(256), 0, stream,
                       x, xsab, xcab, W_o1, b_o1, W_o2, b_o2, gamma, attn_skip, gA);
    hipLaunchKernelGGL((k_conv3m<0>), dim3(512), dim3(256), 0, stream,
                       gA, wb1, bn1_w, bn1_b, (const float*)nullptr, g1,
                       (const short*)nullptr, (const float*)nullptr, (float*)nullptr);
    hipLaunchKernelGGL((k_conv3m<1>), dim3(512), dim3(256), 0, stream,
                       g1, wb2, bn2_w, bn2_b, attn_skip, (short*)nullptr,
                       wb8, conv8b, attn_skip);
}

// Round 11
// 209.608 us; speedup vs baseline: 1.0888x; 1.0122x over previous
//
#include <hip/hip_runtime.h>

#define NTOK 32768

typedef __attribute__((ext_vector_type(8))) short short8;
typedef __attribute__((ext_vector_type(4))) short short4_t;
typedef __attribute__((ext_vector_type(4))) float f32x4;

__device__ __forceinline__ short f2b(float f) {
    union { float f; unsigned u; } v; v.f = f;
    unsigned r = v.u + 0x7fffu + ((v.u >> 16) & 1u);
    return (short)(r >> 16);
}
__device__ __forceinline__ float b2f(short s) {
    union { float f; unsigned u; } v;
    v.u = ((unsigned)(unsigned short)s) << 16;
    return v.f;
}

// ------- setup: repack conv weights, bf16 conversions, init accumulators -------
__global__ void k_repack(const float* __restrict__ w1, const float* __restrict__ w2,
                         const float* __restrict__ w8, const float* __restrict__ wef,
                         const float* __restrict__ wq, const float* __restrict__ bEF,
                         short* __restrict__ wb1, short* __restrict__ wb2,
                         short* __restrict__ wb8, short* __restrict__ wefb,
                         short* __restrict__ wqb, float* __restrict__ kp,
                         float* __restrict__ vp, float* __restrict__ qd)
{
    int i = blockIdx.x * 256 + threadIdx.x;
    if (i >= 2349312) return;
    if (i >= 2347008) { qd[i - 2347008] = 0.f; return; }
    if (i >= 2338816) {
        int j = i - 2338816;
        float v = bEF[j & 63];
        kp[j] = v; vp[j] = v; return;
    }
    if (i >= 2322432) { int j = i - 2322432; wqb[j] = f2b(wq[j]); return; }
    if (i >= 225280)  { int j = i - 225280;  wefb[j] = f2b(wef[j]); return; }
    if (i >= 221184)  { int j = i - 221184;  wb8[j] = f2b(w8[j]); return; }
    int sel = i >= 110592;
    int j = sel ? i - 110592 : i;
    int tap = j >> 12;
    int r = j & 4095;
    int oc = r >> 6, ic = r & 63;
    const float* w = sel ? w2 : w1;
    short* o = sel ? wb2 : wb1;
    o[j] = f2b(w[(oc * 64 + ic) * 27 + tap]);
}

// ---------------- fused LayerNorm + QKVV GEMM (MFMA), bf16 W ----------------
// qkvvb layout: bf16 [isel(4)][b(2)][h(4)][d(16)][N]  (512 rows x 32768 = 32 MB)
__global__ __launch_bounds__(256) void k_ln_qkvv(
    const float* __restrict__ x, const float* __restrict__ lnw,
    const float* __restrict__ lnb, const short* __restrict__ wqb,
    short* __restrict__ qkvvb)
{
    __shared__ __align__(16) short Wl[256 * 72];
    __shared__ __align__(16) short tr[256 * 72];
    __shared__ float red1[4][64], red2[4][64];
    __shared__ float mu_s[64], rs_s[64];
    short* al = tr;                                 // bf16 [64 t][72]

    int bid = blockIdx.x;
    int b = bid >> 9;
    int n0 = (bid & 511) << 6;
    int tid = threadIdx.x;

    for (int i = tid; i < 2048; i += 256) {
        int out = i >> 3, q8 = (i & 7) * 8;
        *(short8*)&Wl[out * 72 + q8] = *(const short8*)&wqb[out * 64 + q8];
    }

    int t = tid & 63, cq = tid >> 6;
    float xr[16];
    float s1 = 0.f, s2 = 0.f;
    const float* xb = x + (((size_t)(b * 64 + cq * 16)) << 15) + n0 + t;
#pragma unroll
    for (int j = 0; j < 16; ++j) {
        float v = xb[(size_t)j << 15];
        xr[j] = v; s1 += v; s2 += v * v;
    }
    red1[cq][t] = s1; red2[cq][t] = s2;
    __syncthreads();
    if (tid < 64) {
        float a = red1[0][tid] + red1[1][tid] + red1[2][tid] + red1[3][tid];
        float q = red2[0][tid] + red2[1][tid] + red2[2][tid] + red2[3][tid];
        float mu = a * (1.f / 64.f);
        float var = q * (1.f / 64.f) - mu * mu;
        mu_s[tid] = mu;
        rs_s[tid] = rsqrtf(var + 1e-5f);
    }
    __syncthreads();
    {
        float mu = mu_s[t], rs = rs_s[t];
        short8 p0, p1;
#pragma unroll
        for (int j = 0; j < 8; ++j) {
            int c = cq * 16 + j;
            p0[j] = f2b((xr[j] - mu) * rs * lnw[c] + lnb[c]);
        }
#pragma unroll
        for (int j = 0; j < 8; ++j) {
            int c = cq * 16 + 8 + j;
            p1[j] = f2b((xr[8 + j] - mu) * rs * lnw[c] + lnb[c]);
        }
        *(short8*)&al[t * 72 + cq * 16] = p0;
        *(short8*)&al[t * 72 + cq * 16 + 8] = p1;
    }
    __syncthreads();

    int w = tid >> 6, lane = tid & 63, l15 = lane & 15, quad = lane >> 4;
    f32x4 acc[4][4];
#pragma unroll
    for (int mt = 0; mt < 4; ++mt)
#pragma unroll
        for (int nt = 0; nt < 4; ++nt) acc[mt][nt] = (f32x4){0.f, 0.f, 0.f, 0.f};
#pragma unroll
    for (int ks = 0; ks < 2; ++ks) {
        short8 af[4], bf[4];
#pragma unroll
        for (int mt = 0; mt < 4; ++mt)
            af[mt] = *(const short8*)&al[(mt * 16 + l15) * 72 + quad * 8 + ks * 32];
#pragma unroll
        for (int nt = 0; nt < 4; ++nt)
            bf[nt] = *(const short8*)&Wl[(w * 64 + nt * 16 + l15) * 72 + quad * 8 + ks * 32];
#pragma unroll
        for (int mt = 0; mt < 4; ++mt)
#pragma unroll
            for (int nt = 0; nt < 4; ++nt)
                acc[mt][nt] = __builtin_amdgcn_mfma_f32_16x16x32_bf16(af[mt], bf[nt], acc[mt][nt], 0, 0, 0);
    }
    __syncthreads();

#pragma unroll
    for (int mt = 0; mt < 4; ++mt)
#pragma unroll
        for (int nt = 0; nt < 4; ++nt) {
            int out = w * 64 + nt * 16 + l15;
            short4_t sv;
#pragma unroll
            for (int r = 0; r < 4; ++r) sv[r] = f2b(acc[mt][nt][r]);
            *(short4_t*)&tr[out * 72 + mt * 16 + quad * 4] = sv;
        }
    __syncthreads();
    for (int i = tid; i < 2048; i += 256) {
        int o = i >> 3, tq = (i & 7) * 8;
        short8 v = *(const short8*)&tr[o * 72 + tq];
        int isel = o >> 6, h = (o >> 4) & 3, d = o & 15;
        *(short8*)&qkvvb[((size_t)(((isel * 2 + b) * 4 + h) * 16 + d) << 15) + n0 + tq] = v;
    }
}

// ------- merged MFMA: k/v projections + q.k logits + L2-norm accumulators -------
__global__ __launch_bounds__(256) void k_pq(
    const short* __restrict__ qkvvb, const short* __restrict__ wefb,
    float* __restrict__ kp, float* __restrict__ vp, float* __restrict__ qd,
    float* __restrict__ qn_acc, float* __restrict__ kn_acc)
{
    __shared__ float redb[3][64][38];
    int kc = blockIdx.x, bh = blockIdx.y;
    int tid = threadIdx.x;
    int w = tid >> 6, lane = tid & 63, l15 = lane & 15, quad = lane >> 4;
    size_t qrow = ((size_t)(bh * 16 + l15)) << 15;
    size_t krow = ((size_t)(128 + bh * 16 + l15)) << 15;
    size_t vrow = ((size_t)(384 + bh * 16 + l15)) << 15;
    int nbase = kc * 1024 + w * 256 + quad * 8;
    f32x4 acck[4], accv[4], accqd, accqq, acckk;
#pragma unroll
    for (int nt = 0; nt < 4; ++nt) {
        acck[nt] = (f32x4){0.f, 0.f, 0.f, 0.f};
        accv[nt] = (f32x4){0.f, 0.f, 0.f, 0.f};
    }
    accqd = (f32x4){0.f, 0.f, 0.f, 0.f};
    accqq = (f32x4){0.f, 0.f, 0.f, 0.f};
    acckk = (f32x4){0.f, 0.f, 0.f, 0.f};
#pragma unroll
    for (int ks = 0; ks < 8; ++ks) {
        int n = nbase + ks * 32;
        short8 qf = *(const short8*)&qkvvb[qrow + n];
        short8 kf = *(const short8*)&qkvvb[krow + n];
        short8 vf = *(const short8*)&qkvvb[vrow + n];
        accqd = __builtin_amdgcn_mfma_f32_16x16x32_bf16(qf, kf, accqd, 0, 0, 0);
        accqq = __builtin_amdgcn_mfma_f32_16x16x32_bf16(qf, qf, accqq, 0, 0, 0);
        acckk = __builtin_amdgcn_mfma_f32_16x16x32_bf16(kf, kf, acckk, 0, 0, 0);
#pragma unroll
        for (int nt = 0; nt < 4; ++nt) {
            short8 wf = *(const short8*)&wefb[(((size_t)(nt * 16 + l15)) << 15) + n];
            acck[nt] = __builtin_amdgcn_mfma_f32_16x16x32_bf16(kf, wf, acck[nt], 0, 0, 0);
            accv[nt] = __builtin_amdgcn_mfma_f32_16x16x32_bf16(vf, wf, accv[nt], 0, 0, 0);
        }
    }
    int diag = (quad == (l15 >> 2));
    float qqv = diag ? accqq[l15 & 3] : 0.f;
    float kkv = diag ? acckk[l15 & 3] : 0.f;
    if (w > 0) {
        float* p = &redb[w - 1][lane][0];
#pragma unroll
        for (int nt = 0; nt < 4; ++nt)
#pragma unroll
            for (int r = 0; r < 4; ++r) { p[nt * 4 + r] = acck[nt][r]; p[16 + nt * 4 + r] = accv[nt][r]; }
#pragma unroll
        for (int r = 0; r < 4; ++r) p[32 + r] = accqd[r];
        p[36] = qqv; p[37] = kkv;
    }
    __syncthreads();
    if (w == 0) {
#pragma unroll
        for (int wv = 0; wv < 3; ++wv) {
            const float* p = &redb[wv][lane][0];
#pragma unroll
            for (int nt = 0; nt < 4; ++nt)
#pragma unroll
                for (int r = 0; r < 4; ++r) { acck[nt][r] += p[nt * 4 + r]; accv[nt][r] += p[16 + nt * 4 + r]; }
#pragma unroll
            for (int r = 0; r < 4; ++r) accqd[r] += p[32 + r];
            qqv += p[36]; kkv += p[37];
        }
        int d = quad * 4;
#pragma unroll
        for (int nt = 0; nt < 4; ++nt)
#pragma unroll
            for (int r = 0; r < 4; ++r) {
                int idx = (bh * 16 + d + r) * 64 + nt * 16 + l15;
                atomicAdd(&kp[idx], acck[nt][r]);
                atomicAdd(&vp[idx], accv[nt][r]);
            }
#pragma unroll
        for (int r = 0; r < 4; ++r)
            atomicAdd(&qd[bh * 256 + (d + r) * 16 + l15], accqd[r]);
        if (diag) {
            atomicAdd(&qn_acc[bh * 16 + l15], qqv);
            atomicAdd(&kn_acc[bh * 16 + l15], kkv);
        }
    }
}

// ---------------- fused x_ca + spatial attention — MFMA, bf16-staged frags ----------------
// Round-11: all LDS operands staged as bf16 in MFMA-ready layouts so every
// fragment is ONE ds_read_b128 (was: 32-90 scalar float LDS reads + 200+ VALU
// b2f/fmul/f2b per wave on the serial chain):
//  klT[64p][24] bf16 = Kp^T PRE-SCALED by iq[d] (fold Q-normalization into K:
//    sum_d (q*iq)*k == sum_d q*(k*iq)) -> qb is raw short8 loads, zero math.
//  vlb[16d][72] bf16 -> vb = 2 vector reads.  alcab[16][24] bf16 from CA softmax.
// Pl stays 4x16x72 (r10 fused softmax->PV). LDS ~24KB, 5 blocks/CU (VGPR cap).
__global__ __launch_bounds__(256) void k_attn(
    const short* __restrict__ qkvvb, const float* __restrict__ qd,
    const float* __restrict__ qn_acc, const float* __restrict__ kn_acc,
    const float* __restrict__ temp1, const float* __restrict__ kp,
    const float* __restrict__ vp, const float* __restrict__ temp2,
    short* __restrict__ xsab, short* __restrict__ xcab)
{
    __shared__ __align__(16) short klT[64 * 24];    // bf16 [p][d], pre-scaled by iq[d]
    __shared__ __align__(16) short vlb[16 * 72];    // bf16 [d][p]
    __shared__ __align__(16) short alcab[16 * 24];  // bf16 [r][e]
    __shared__ float iqs[16], iks[16];
    __shared__ __align__(16) short Pl[4][16][72];   // per-wave 16-token P tile, XOR-swizzled cols
    __shared__ short Ol[4][64][17];                 // per-wave O transpose staging
    int bh = blockIdx.y; int b = bh >> 2, h = bh & 3;
    int tid = threadIdx.x;
    // phase 1: inverse norms
    if (tid < 32) {
        int j = tid & 15;
        float v = (tid < 16) ? qn_acc[bh * 16 + j] : kn_acc[bh * 16 + j];
        float rv = 1.f / fmaxf(sqrtf(v), 1e-12f);
        if (tid < 16) iqs[j] = rv; else iks[j] = rv;
    }
    __syncthreads();
    // phase 2: stage klT (iq-scaled, transposed), vlb, CA softmax -> alcab
    for (int i = tid; i < 1024; i += 256) {
        int d = i >> 6, p = i & 63;
        klT[p * 24 + d] = f2b(kp[bh * 1024 + i] * iqs[d]);
        vlb[d * 72 + p] = f2b(vp[bh * 1024 + i]);
    }
    {   // CA softmax: row r = tid>>4 (lanes r*16..r*16+15 contiguous in-wave)
        int r = tid >> 4, e = tid & 15;
        float v = qd[bh * 256 + tid] * iqs[r] * iks[e] * temp1[h];
        float mx = v;
#pragma unroll
        for (int m = 1; m < 16; m <<= 1) mx = fmaxf(mx, __shfl_xor(mx, m));
        float ex = __expf(v - mx);
        float s = ex;
#pragma unroll
        for (int m = 1; m < 16; m <<= 1) s += __shfl_xor(s, m);
        alcab[r * 24 + e] = f2b(ex / s);
    }
    __syncthreads();

    int w = tid >> 6, lane = tid & 63, l15 = lane & 15, quad = lane >> 4;
    int tw = (blockIdx.x << 8) + w * 64;
    float t2 = temp2[h];
    const short8 zero8 = {0, 0, 0, 0, 0, 0, 0, 0};
    int xs = (l15 & 7) << 3;                        // Pl bank swizzle (per token row)

    // ---- B-frags: raw Q[tok][d] shorts (iq folded into klT); k zero-pad 16..31 ----
    short8 qb[4];
    if (quad < 2) {
#pragma unroll
        for (int tnt = 0; tnt < 4; ++tnt) {
            short8 v;
#pragma unroll
            for (int j = 0; j < 8; ++j) {
                int d = quad * 8 + j;
                v[j] = qkvvb[(((size_t)(bh * 16 + d)) << 15) + tw + tnt * 16 + l15];
            }
            qb[tnt] = v;
        }
    } else {
#pragma unroll
        for (int tnt = 0; tnt < 4; ++tnt) qb[tnt] = zero8;
    }
    // ---- A-frags: Kp*iq from klT — one ds_read_b128 each ----
    short8 ka[4];
    if (quad < 2) {
#pragma unroll
        for (int pmt = 0; pmt < 4; ++pmt)
            ka[pmt] = *(const short8*)&klT[(pmt * 16 + l15) * 24 + quad * 8];
    } else {
#pragma unroll
        for (int pmt = 0; pmt < 4; ++pmt) ka[pmt] = zero8;
    }

    // ---- S^T = (Kp*iq) . Q^T : 16 MFMAs ----
    f32x4 st[4][4];
#pragma unroll
    for (int pmt = 0; pmt < 4; ++pmt)
#pragma unroll
        for (int tnt = 0; tnt < 4; ++tnt) st[pmt][tnt] = (f32x4){0.f, 0.f, 0.f, 0.f};
#pragma unroll
    for (int pmt = 0; pmt < 4; ++pmt)
#pragma unroll
        for (int tnt = 0; tnt < 4; ++tnt)
            st[pmt][tnt] = __builtin_amdgcn_mfma_f32_16x16x32_bf16(ka[pmt], qb[tnt], st[pmt][tnt], 0, 0, 0);

    // ---- Vp B-frags from vlb — one ds_read_b128 each ----
    short8 vb[2];
#pragma unroll
    for (int ks = 0; ks < 2; ++ks)
        vb[ks] = *(const short8*)&vlb[l15 * 72 + quad * 8 + ks * 32];

    // ---- fused: per 16-token tile, softmax over p -> Pl (rows l15) -> PV MFMA ----
    f32x4 vo[4];
#pragma unroll
    for (int tnt = 0; tnt < 4; ++tnt) {
        float v[16];
        float mx = -1e30f;
#pragma unroll
        for (int pmt = 0; pmt < 4; ++pmt)
#pragma unroll
            for (int r = 0; r < 4; ++r) {
                float x = st[pmt][tnt][r] * t2;
                v[pmt * 4 + r] = x; mx = fmaxf(mx, x);
            }
        mx = fmaxf(mx, __shfl_xor(mx, 16));
        mx = fmaxf(mx, __shfl_xor(mx, 32));
        float s = 0.f;
#pragma unroll
        for (int i2 = 0; i2 < 16; ++i2) { v[i2] = __expf(v[i2] - mx); s += v[i2]; }
        s += __shfl_xor(s, 16);
        s += __shfl_xor(s, 32);
        float inv = 1.f / s;
#pragma unroll
        for (int pmt = 0; pmt < 4; ++pmt)
#pragma unroll
            for (int t = 0; t < 2; ++t) {
                unsigned lo = (unsigned short)f2b(v[pmt * 4 + 2 * t] * inv);
                unsigned hi = (unsigned short)f2b(v[pmt * 4 + 2 * t + 1] * inv);
                int col = (pmt * 16 + quad * 4 + 2 * t) ^ xs;
                *(unsigned*)&Pl[w][l15][col] = lo | (hi << 16);
            }
        // wave-internal write->read: compiler inserts lgkmcnt; no barrier needed
        vo[tnt] = (f32x4){0.f, 0.f, 0.f, 0.f};
#pragma unroll
        for (int ks = 0; ks < 2; ++ks) {
            short8 pa = *(const short8*)&Pl[w][l15][(quad * 8 + ks * 32) ^ xs];
            vo[tnt] = __builtin_amdgcn_mfma_f32_16x16x32_bf16(pa, vb[ks], vo[tnt], 0, 0, 0);
        }
    }

    // ---- CA: x_ca = Vca . alca^T (k = e, zero-padded 16..31) ----
    short8 ab[4], bb;
    if (quad < 2) {
        bb = *(const short8*)&alcab[l15 * 24 + quad * 8];
#pragma unroll
        for (int mt = 0; mt < 4; ++mt) {
            short8 u;
#pragma unroll
            for (int j = 0; j < 8; ++j)
                u[j] = qkvvb[(((size_t)(256 + bh * 16 + quad * 8 + j)) << 15) + tw + mt * 16 + l15];
            ab[mt] = u;
        }
    } else {
        bb = zero8;
#pragma unroll
        for (int mt = 0; mt < 4; ++mt) ab[mt] = zero8;
    }
    f32x4 ca[4];
#pragma unroll
    for (int mt = 0; mt < 4; ++mt) ca[mt] = (f32x4){0.f, 0.f, 0.f, 0.f};
#pragma unroll
    for (int mt = 0; mt < 4; ++mt)
        ca[mt] = __builtin_amdgcn_mfma_f32_16x16x32_bf16(ab[mt], bb, ca[mt], 0, 0, 0);

    // ---- CA direct stores (lane: tok=mt*16+quad*4+r, d=l15; 32B-coalesced) ----
#pragma unroll
    for (int mt = 0; mt < 4; ++mt)
#pragma unroll
        for (int r = 0; r < 4; ++r) {
            int tok = tw + mt * 16 + quad * 4 + r;
            xcab[((size_t)(b * NTOK + tok)) * 64 + h * 16 + l15] = f2b(ca[mt][r]);
        }

    // ---- O via LDS transpose -> token-coalesced xsab writes ----
#pragma unroll
    for (int mt = 0; mt < 4; ++mt)
#pragma unroll
        for (int r = 0; r < 4; ++r)
            Ol[w][mt * 16 + quad * 4 + r][l15] = f2b(vo[mt][r]);
#pragma unroll
    for (int d = 0; d < 16; ++d) {
        short vv = Ol[w][lane][d];
        xsab[(size_t)b * 2097152 + (((size_t)(d * 4 + h)) << 15) + tw + lane] = vv;
    }
}

// ---------------- EPA epilogue (MFMA): proj + gamma + residual ----------------
__global__ __launch_bounds__(256) void k_epilogue(
    const float* __restrict__ x, const short* __restrict__ xsab,
    const short* __restrict__ xcab, const float* __restrict__ Wo1,
    const float* __restrict__ bo1, const float* __restrict__ Wo2,
    const float* __restrict__ bo2, const float* __restrict__ gamma,
    float* __restrict__ attn_skip, short* __restrict__ gA)
{
    __shared__ __align__(16) short Wl[64 * 72];    // rows 0-31: Wo1, 32-63: Wo2 (bf16)
    __shared__ __align__(16) short trS[256 * 72];  // bf16 [256 tok][72] for gA transpose
    int tid = threadIdx.x;
    int bidx = blockIdx.x;
    int b = bidx >> 7;
    int n0 = (bidx & 127) << 8;                    // 256 tokens per block
    for (int i = tid; i < 4096; i += 256) {
        int row = i >> 6, c = i & 63;
        float wv = (row < 32) ? Wo1[row * 64 + c] : Wo2[(row - 32) * 64 + c];
        Wl[row * 72 + c] = f2b(wv);
    }
    __syncthreads();

    int w = tid >> 6, lane = tid & 63, l15 = lane & 15, quad = lane >> 4;
    int tw = n0 + w * 64;
    const short* sa_base = xsab + (size_t)b * 2097152;
    const short* ca_base = xcab + (size_t)b * 2097152;

    f32x4 acc_sa[4][2], acc_ca[4][2];
#pragma unroll
    for (int mt = 0; mt < 4; ++mt)
#pragma unroll
        for (int nt = 0; nt < 2; ++nt) {
            acc_sa[mt][nt] = (f32x4){0.f, 0.f, 0.f, 0.f};
            acc_ca[mt][nt] = (f32x4){0.f, 0.f, 0.f, 0.f};
        }
#pragma unroll
    for (int ks = 0; ks < 2; ++ks) {
        int ko = quad * 8 + ks * 32;
        short8 b1[2], b2[2];
#pragma unroll
        for (int nt = 0; nt < 2; ++nt) {
            b1[nt] = *(const short8*)&Wl[(nt * 16 + l15) * 72 + ko];
            b2[nt] = *(const short8*)&Wl[(32 + nt * 16 + l15) * 72 + ko];
        }
#pragma unroll
        for (int mt = 0; mt < 4; ++mt) {
            int trow = tw + mt * 16 + l15;
            short8 a1 = *(const short8*)&sa_base[(size_t)trow * 64 + ko];
            short8 a2 = *(const short8*)&ca_base[(size_t)trow * 64 + ko];
#pragma unroll
            for (int nt = 0; nt < 2; ++nt) {
                acc_sa[mt][nt] = __builtin_amdgcn_mfma_f32_16x16x32_bf16(a1, b1[nt], acc_sa[mt][nt], 0, 0, 0);
                acc_ca[mt][nt] = __builtin_amdgcn_mfma_f32_16x16x32_bf16(a2, b2[nt], acc_ca[mt][nt], 0, 0, 0);
            }
        }
    }

    // fused residual: v = x + gamma*(acc + bias); write attn_skip (f32x4/lane);
    // stash bf16 into trS row=token (one scalar store per token — C rows differ!)
#pragma unroll
    for (int half = 0; half < 2; ++half) {   // 0: sa -> c in [0,32), 1: ca -> c in [32,64)
#pragma unroll
        for (int nt = 0; nt < 2; ++nt) {
            int c = half * 32 + nt * 16 + l15;
            float g = gamma[c];
            float bias = half ? bo2[c - 32] : bo1[c];
#pragma unroll
            for (int mt = 0; mt < 4; ++mt) {
                f32x4 a = half ? acc_ca[mt][nt] : acc_sa[mt][nt];
                int tbase = tw + mt * 16 + quad * 4;
                size_t gidx = (((size_t)(b * 64 + c)) << 15) + tbase;
                f32x4 xv = *(const f32x4*)&x[gidx];
                f32x4 o;
#pragma unroll
                for (int r = 0; r < 4; ++r) {
                    float v = xv[r] + g * (a[r] + bias);
                    o[r] = v;
                    trS[(w * 64 + mt * 16 + quad * 4 + r) * 72 + c] = f2b(v);
                }
                *(f32x4*)&attn_skip[gidx] = o;
            }
        }
    }
    __syncthreads();
    // coalesced NHWC gA write
    for (int i = tid; i < 2048; i += 256) {
        int tok = i >> 3, cq = (i & 7) * 8;
        short8 v = *(const short8*)&trS[tok * 72 + cq];
        *(short8*)&gA[((size_t)(b * NTOK + n0 + tok)) * 64 + cq] = v;
    }
}

// ---------------- MFMA implicit-GEMM 3x3x3 conv (round-8 proven) ----------------
template <int MODE>
__global__ __launch_bounds__(256) void k_conv3m(
    const short* __restrict__ gin, const short* __restrict__ wb,
    const float* __restrict__ bnw, const float* __restrict__ bnb,
    const float* __restrict__ skip, short* __restrict__ goutS,
    const short* __restrict__ wb8, const float* __restrict__ b8,
    float* __restrict__ io)
{
    __shared__ __align__(16) short inl_s[24480];   // [3z][6y][34x][40 icpad]
    __shared__ __align__(16) short wl_s[15360];    // 2 x [3][64][40]; MODE1 epi: a2(9216)+w8[64][80]@9216
    int bx = blockIdx.x;
    int bb = bx >> 8;
    int z0 = (bx >> 3) & 31;
    int y0 = (bx & 7) * 4;
    int tid = threadIdx.x;
    int lane = tid & 63, wv = tid >> 6;
    int l15 = lane & 15, quad = lane >> 4;
    int wo = tid >> 2, wq = tid & 3;

    f32x4 acc[2][4];
#pragma unroll
    for (int s = 0; s < 2; ++s)
#pragma unroll
        for (int nt = 0; nt < 4; ++nt) acc[s][nt] = (f32x4){0.f, 0.f, 0.f, 0.f};

    for (int chunk = 0; chunk < 2; ++chunk) {
        const short* wck = wb + chunk * 32 + wq * 8;
        // prefetch stages 0 AND 1 into regs (2-deep rotation)
        short8 wr[2][3];
#pragma unroll
        for (int t = 0; t < 3; ++t) {
            wr[0][t] = *(const short8*)&wck[(size_t)(t * 64 + wo) * 64];
            wr[1][t] = *(const short8*)&wck[(size_t)((3 + t) * 64 + wo) * 64];
        }
        __syncthreads();   // prev chunk's inl_s reads + wl_s buf reads done
        for (int i = tid; i < 2448; i += 256) {
            int p = i >> 2, icq = i & 3;
            int xi = p % 34; int t2 = p / 34; int yi = t2 % 6; int zi = t2 / 6;
            int gz = z0 + zi - 1, gy = y0 + yi - 1, gx = xi - 1;
            short8 v = {0, 0, 0, 0, 0, 0, 0, 0};
            if ((unsigned)gz < 32u && (unsigned)gy < 32u && (unsigned)gx < 32u)
                v = *(const short8*)&gin[((size_t)(bb * NTOK + gz * 1024 + gy * 32 + gx)) * 64 + chunk * 32 + icq * 8];
            *(short8*)&inl_s[p * 40 + icq * 8] = v;
        }
        // write stage-0 weights to buf0
#pragma unroll
        for (int t = 0; t < 3; ++t)
            *(short8*)&wl_s[(t * 64 + wo) * 40 + wq * 8] = wr[0][t];

#pragma unroll
        for (int kz = 0; kz < 3; ++kz)
#pragma unroll
        for (int ky = 0; ky < 3; ++ky) {
            const int sidx = kz * 3 + ky;
            __syncthreads();   // buf[sidx&1] writes visible; buf[(sidx+1)&1] reads (stage sidx-1) done
            if (sidx < 7) {
                // load stage sidx+2 into the slot just freed (held stage sidx)
#pragma unroll
                for (int t = 0; t < 3; ++t)
                    wr[sidx & 1][t] = *(const short8*)&wck[(size_t)(((sidx + 2) * 3 + t) * 64 + wo) * 64];
            }
            const short* wcur = &wl_s[(sidx & 1) * 7680];
            int rowb = (kz * 6 + wv + ky) * 34;
#pragma unroll
            for (int kx = 0; kx < 3; ++kx) {
                short8 bf[4];
#pragma unroll
                for (int nt = 0; nt < 4; ++nt)
                    bf[nt] = *(const short8*)&wcur[(kx * 64 + nt * 16 + l15) * 40 + quad * 8];
#pragma unroll
                for (int s = 0; s < 2; ++s) {
                    short8 af = *(const short8*)&inl_s[(rowb + s * 16 + l15 + kx) * 40 + quad * 8];
#pragma unroll
                    for (int nt = 0; nt < 4; ++nt)
                        acc[s][nt] = __builtin_amdgcn_mfma_f32_16x16x32_bf16(af, bf[nt], acc[s][nt], 0, 0, 0);
                }
            }
            if (sidx < 8) {
                // write stage sidx+1 (loaded at stage sidx-1 -> fully landed)
                short* wnext = &wl_s[((sidx + 1) & 1) * 7680];
#pragma unroll
                for (int t = 0; t < 3; ++t)
                    *(short8*)&wnext[(t * 64 + wo) * 40 + wq * 8] = wr[(sidx + 1) & 1][t];
            }
        }
    }
    __syncthreads();
    float rb = rsqrtf(1.f + 1e-5f);
    if (MODE == 0) {
        short* outS = inl_s;  // [128 pos][72 pad] bf16
#pragma unroll
        for (int nt = 0; nt < 4; ++nt) {
            int oc = nt * 16 + l15;
            float sc_ = bnw[oc] * rb, sh_ = bnb[oc];
#pragma unroll
            for (int s = 0; s < 2; ++s) {
                f32x4 v = acc[s][nt];
#pragma unroll
                for (int r = 0; r < 4; ++r) {
                    int pos = wv * 32 + s * 16 + quad * 4 + r;
                    float val = v[r] * sc_ + sh_;
                    val = val >= 0.f ? val : 0.01f * val;
                    outS[pos * 72 + oc] = f2b(val);
                }
            }
        }
        __syncthreads();
        for (int i = tid; i < 1024; i += 256) {
            int p = i >> 3, cq = i & 7;
            short8 v = *(const short8*)&outS[p * 72 + cq * 8];
            int y = p >> 5, x = p & 31;
            *(short8*)&goutS[((size_t)(bb * NTOK + z0 * 1024 + (y0 + y) * 32 + x)) * 64 + cq * 8] = v;
        }
    } else {
        short* a2_s = wl_s;            // [128 pos][72 pad] bf16 (9216 shorts)
        short* w8_s = wl_s + 9216;     // [64 out][80 pad] bf16 (5120 shorts)
        f32x4 skr[2][4];
        // direct: bn+skip+lrelu from accumulators -> a2_s (pos = wv*32+s*16+quad*4+r)
#pragma unroll
        for (int nt = 0; nt < 4; ++nt) {
            int oc = nt * 16 + l15;
            float sc_ = bnw[oc] * rb, sh_ = bnb[oc];
#pragma unroll
            for (int s = 0; s < 2; ++s) {
                size_t g = (((size_t)(bb * 64 + oc)) << 15) +
                           ((z0 * 32 + y0 + wv) * 32 + s * 16 + quad * 4);
                f32x4 sk = *(const f32x4*)&skip[g];
                skr[s][nt] = sk;
                f32x4 v = acc[s][nt];
#pragma unroll
                for (int r = 0; r < 4; ++r) {
                    int pos = wv * 32 + s * 16 + quad * 4 + r;
                    float val = v[r] * sc_ + sh_ + sk[r];
                    val = val >= 0.f ? val : 0.01f * val;
                    a2_s[pos * 72 + oc] = f2b(val);
                }
            }
        }
        // stage w8 bf16 [64 out][80 pad]
        for (int i = tid; i < 512; i += 256) {
            int ocw = i >> 3, cq = i & 7;
            *(short8*)&w8_s[ocw * 80 + cq * 8] = *(const short8*)&wb8[ocw * 64 + cq * 8];
        }
        __syncthreads();
        f32x4 acc2[2][4];
#pragma unroll
        for (int s = 0; s < 2; ++s)
#pragma unroll
            for (int nt = 0; nt < 4; ++nt) acc2[s][nt] = (f32x4){0.f, 0.f, 0.f, 0.f};
#pragma unroll
        for (int ks = 0; ks < 2; ++ks) {
            short8 a8[2], b8f[4];
#pragma unroll
            for (int s = 0; s < 2; ++s)
                a8[s] = *(const short8*)&a2_s[(wv * 32 + s * 16 + l15) * 72 + quad * 8 + ks * 32];
#pragma unroll
            for (int nt = 0; nt < 4; ++nt)
                b8f[nt] = *(const short8*)&w8_s[(nt * 16 + l15) * 80 + quad * 8 + ks * 32];
#pragma unroll
            for (int s = 0; s < 2; ++s)
#pragma unroll
                for (int nt = 0; nt < 4; ++nt)
                    acc2[s][nt] = __builtin_amdgcn_mfma_f32_16x16x32_bf16(a8[s], b8f[nt], acc2[s][nt], 0, 0, 0);
        }
        // direct io write from acc2 (same pos->(y=wv, x) mapping), fused skip+bias
#pragma unroll
        for (int nt = 0; nt < 4; ++nt) {
            int oc = nt * 16 + l15;
            float bias8 = b8[oc];
#pragma unroll
            for (int s = 0; s < 2; ++s) {
                size_t g = (((size_t)(bb * 64 + oc)) << 15) +
                           ((z0 * 32 + y0 + wv) * 32 + s * 16 + quad * 4);
                f32x4 o;
#pragma unroll
                for (int r = 0; r < 4; ++r) o[r] = skr[s][nt][r] + acc2[s][nt][r] + bias8;
                *(f32x4*)&io[g] = o;
            }
        }
    }
}

extern "C" void kernel_launch(void* const* d_in, const int* in_sizes, int n_in,
                              void* d_out, int out_size, void* d_ws, size_t ws_size,
                              hipStream_t stream) {
    const float* x      = (const float*)d_in[0];
    const float* ln_w   = (const float*)d_in[1];
    const float* ln_b   = (const float*)d_in[2];
    const float* gamma  = (const float*)d_in[3];
    const float* temp1  = (const float*)d_in[4];
    const float* temp2  = (const float*)d_in[5];
    const float* W_qkvv = (const float*)d_in[6];
    const float* W_EF   = (const float*)d_in[7];
    const float* b_EF   = (const float*)d_in[8];
    const float* W_o1   = (const float*)d_in[9];
    const float* b_o1   = (const float*)d_in[10];
    const float* W_o2   = (const float*)d_in[11];
    const float* b_o2   = (const float*)d_in[12];
    const float* conv1w = (const float*)d_in[13];
    const float* conv2w = (const float*)d_in[14];
    const float* bn1_w  = (const float*)d_in[15];
    const float* bn1_b  = (const float*)d_in[16];
    const float* bn2_w  = (const float*)d_in[17];
    const float* bn2_b  = (const float*)d_in[18];
    const float* conv8w = (const float*)d_in[19];
    const float* conv8b = (const float*)d_in[20];

    // qkvvb = 512 rows x 32768 = 16,777,216 shorts (32 MB); all else after it.
    short* qkvvb = (short*)d_ws;                 // [0, 16777216) shorts
    float* kp    = (float*)(qkvvb + 16777216);   // 8192 floats
    float* vp    = kp + 8192;                    // 8192
    float* qd    = vp + 8192;                    // 2048
    float* qn_acc= qd + 2048;                    // 128
    float* kn_acc= qn_acc + 128;                 // 128
    float* a_ca  = kn_acc + 128;                 // 2048 (unused)
    float* iqn   = a_ca + 2048;                  // 128  (unused)
    float* ikn   = iqn + 128;                    // 128  (unused)
    short* xcab  = (short*)(ikn + 128);          // 4194304 shorts
    short* xsab  = xcab + 4194304;               // 4194304
    short* gA    = xsab + 4194304;               // 4194304
    short* g1    = gA + 4194304;                 // 4194304
    short* wb1   = g1 + 4194304;                 // 110592
    short* wb2   = wb1 + 110592;                 // 110592
    short* wb8   = wb2 + 110592;                 // 4096
    short* wefb  = wb8 + 4096;                   // 2097152
    short* wqb   = wefb + 2097152;               // 16384

    float* attn_skip = (float*)d_out;

    hipLaunchKernelGGL(k_repack, dim3(9177), dim3(256), 0, stream,
                       conv1w, conv2w, conv8w, W_EF, W_qkvv, b_EF,
                       wb1, wb2, wb8, wefb, wqb, kp, vp, qd);
    hipLaunchKernelGGL(k_ln_qkvv, dim3(1024), dim3(256), 0, stream,
                       x, ln_w, ln_b, wqb, qkvvb);
    hipLaunchKernelGGL(k_pq, dim3(32, 8), dim3(256), 0, stream,
                       qkvvb, wefb, kp, vp, qd, qn_acc, kn_acc);
    hipLaunchKernelGGL(k_attn, dim3(128, 8), dim3(256), 0, stream,
                       qkvvb, qd, qn_acc, kn_acc, temp1, kp, vp, temp2, xsab, xcab);
    hipLaunchKernelGGL(k_epilogue, dim3(256), dim3(256), 0, stream,
                       x, xsab, xcab, W_o1, b_o1, W_o2, b_o2, gamma, attn_skip, gA);
    hipLaunchKernelGGL((k_conv3m<0>), dim3(512), dim3(256), 0, stream,
                       gA, wb1, bn1_w, bn1_b, (const float*)nullptr, g1,
                       (const short*)nullptr, (const float*)nullptr, (float*)nullptr);
    hipLaunchKernelGGL((k_conv3m<1>), dim3(512), dim3(256), 0, stream,
                       g1, wb2, bn2_w, bn2_b, attn_skip, (short*)nullptr,
                       wb8, conv8b, attn_skip);
}